// Round 19
// baseline (5322.293 us; speedup 1.0000x reference)
//
#include <hip/hip_runtime.h>
#include <hip/hip_bf16.h>
#include <cstdint>
#include <math.h>

#define N_TOK 8192
#define D_DIM 1024
#define F_DIM 4096
#define NE 8
#define CAP 8192
#define MAXT 72    // max sum_e ceil(cnt_e/256) = 71, padded

typedef __attribute__((ext_vector_type(8))) short short8;
typedef __attribute__((ext_vector_type(4))) short short4v;
typedef __attribute__((ext_vector_type(4))) float f32x4;

__device__ __forceinline__ short f2bf(float f) {
  __bf16 b = (__bf16)f;
  return *(short*)&b;
}
__device__ __forceinline__ float bf2f(short u) {
  union { unsigned int i; float f; } c;
  c.i = ((unsigned int)(unsigned short)u) << 16;
  return c.f;
}
__device__ __forceinline__ void gload(const void* g, void* l) {
  __builtin_amdgcn_global_load_lds(
      (const __attribute__((address_space(1))) uint32_t*)g,
      (__attribute__((address_space(3))) uint32_t*)l, 16, 0, 0);
}

// ---------------- gating + fused X->bf16 ------------------------------------
__global__ __launch_bounds__(256) void gate_kernel(
    const float* __restrict__ X, const float* __restrict__ Wg,
    const float* __restrict__ bg, int* __restrict__ cnt,
    int* __restrict__ bucket, float* __restrict__ pairw,
    unsigned short* __restrict__ Xb)
{
  const int token = blockIdx.x;
  const int tid = threadIdx.x;
  const float4* x4 = (const float4*)(X + (size_t)token * D_DIM);
  const float4* wg4 = (const float4*)Wg;
  float part[NE];
#pragma unroll
  for (int e = 0; e < NE; ++e) part[e] = 0.f;
  const float4 xv = x4[tid];
#pragma unroll
  for (int e = 0; e < NE; ++e) {
    const float4 wv = wg4[e * (D_DIM / 4) + tid];
    part[e] = fmaf(xv.x, wv.x, fmaf(xv.y, wv.y, fmaf(xv.z, wv.z, fmaf(xv.w, wv.w, part[e]))));
  }
  short4v o;
  o.x = f2bf(xv.x); o.y = f2bf(xv.y); o.z = f2bf(xv.z); o.w = f2bf(xv.w);
  ((short4v*)(Xb + (size_t)token * D_DIM))[tid] = o;

#pragma unroll
  for (int e = 0; e < NE; ++e) {
#pragma unroll
    for (int off = 32; off > 0; off >>= 1) part[e] += __shfl_down(part[e], off);
  }
  __shared__ float wsum[4][NE];
  const int wave = tid >> 6;
  if ((tid & 63) == 0) {
#pragma unroll
    for (int e = 0; e < NE; ++e) wsum[wave][e] = part[e];
  }
  __syncthreads();
  if (tid == 0) {
    float lg[NE];
#pragma unroll
    for (int e = 0; e < NE; ++e)
      lg[e] = wsum[0][e] + wsum[1][e] + wsum[2][e] + wsum[3][e] + bg[e];
    int e0 = 0;
#pragma unroll
    for (int e = 1; e < NE; ++e) if (lg[e] > lg[e0]) e0 = e;     // jax tie-break: lower idx
    int e1 = (e0 == 0) ? 1 : 0;
#pragma unroll
    for (int e = 0; e < NE; ++e) if (e != e0 && lg[e] > lg[e1]) e1 = e;
    float p1 = expf(lg[e1] - lg[e0]);            // p0 = 1; softmax denom cancels
    float inv = 1.f / (1.f + p1);
    pairw[token * 2]     = inv;
    pairw[token * 2 + 1] = p1 * inv;
    int pos0 = atomicAdd(&cnt[e0], 1);
    bucket[e0 * CAP + pos0] = token * 2;
    int pos1 = atomicAdd(&cnt[e1], 1);
    bucket[e1 * CAP + pos1] = token * 2 + 1;
  }
}

// ---------------- prefix sums + pair->slot map (one launch) -----------------
__global__ __launch_bounds__(256) void prefix_fill_kernel(
    const int* __restrict__ cnt, int* __restrict__ expoff,
    int* __restrict__ toff, const int* __restrict__ bucket,
    int* __restrict__ pairslot)
{
  __shared__ int soff[NE];
  if (threadIdx.x == 0) {
    int s = 0, t = 0;
#pragma unroll
    for (int e = 0; e < NE; ++e) {
      expoff[e] = s; soff[e] = s;
      toff[e] = t;
      s += cnt[e];
      t += (cnt[e] + 255) >> 8;
    }
    toff[NE] = t;
  }
  __syncthreads();
  for (int e = 0; e < NE; ++e) {
    const int n = cnt[e], off = soff[e];
    for (int p = threadIdx.x; p < n; p += 256)
      pairslot[bucket[e * CAP + p]] = off + p;
  }
}

// ---------------- both weight transposes in ONE launch ----------------------
__global__ __launch_bounds__(256) void transpose_both_kernel(
    const float* __restrict__ W1, const float* __restrict__ W2,
    unsigned short* __restrict__ W1t, unsigned short* __restrict__ W2t)
{
  __shared__ float tileT[64][68];
  const int z = blockIdx.z;
  const bool is1 = (z < NE);
  const int ez = is1 ? z : z - NE;
  const int R = is1 ? D_DIM : F_DIM;
  const int C = is1 ? F_DIM : D_DIM;
  const float* src = (is1 ? W1 : W2) + (size_t)ez * D_DIM * F_DIM;
  unsigned short* dst = (is1 ? W1t : W2t) + (size_t)ez * D_DIM * F_DIM;
  const int c0 = (is1 ? blockIdx.x : blockIdx.y) * 64;
  const int r0 = (is1 ? blockIdx.y : blockIdx.x) * 64;
  const int tid = threadIdx.x;
  const int cx = tid & 15;
  const int ry = tid >> 4;
#pragma unroll
  for (int i = 0; i < 4; ++i) {
    const int row = ry + i * 16;
    const float4 v = *(const float4*)(src + (size_t)(r0 + row) * C + c0 + cx * 4);
    tileT[cx * 4 + 0][row] = v.x;
    tileT[cx * 4 + 1][row] = v.y;
    tileT[cx * 4 + 2][row] = v.z;
    tileT[cx * 4 + 3][row] = v.w;
  }
  __syncthreads();
#pragma unroll
  for (int i = 0; i < 4; ++i) {
    const int cc = ry + i * 16;
    const float4 v = *(const float4*)(&tileT[cc][cx * 4]);
    short4v o;
    o.x = f2bf(v.x); o.y = f2bf(v.y); o.z = f2bf(v.z); o.w = f2bf(v.w);
    *(short4v*)(dst + (size_t)(c0 + cc) * R + r0 + cx * 4) = o;
  }
}

// ---------------- grouped expert GEMM: 256x256, 32 waves/CU, ring-2 ---------
// R18 core (224 us) with ring-2 LDS (64 KB + rowpair = 65 KB) so TWO
// 1024-thread blocks co-reside -> 32 waves/CU (HW max). The DMA staging rate
// scales with resident waves (R15 8w: 7 B/cyc; R18 16w: 8.4; R7 2-block:
// 9.5); this is the last untested cell. Schedule per half H (2-phase ledger):
// read frags(H) -> stage(H+1) into other slot (WAR-safe: its reads completed
// at H-1 before H's top barrier) -> lgkmcnt(0) -> setprio + 16 MFMA ->
// vmcnt(0) -> barrier. The drain is issued ds-burst+MFMA after the stage;
// residual latency overlaps the co-resident block (R7 mechanism x4 waves).
template<int LAYER>
__global__ __launch_bounds__(1024, 8) void moe_gemm(
    const unsigned short* __restrict__ Abase,
    const unsigned short* __restrict__ Bt,
    const float* __restrict__ bias,
    const int* __restrict__ cnt,
    const int* __restrict__ expoff,
    const int* __restrict__ toff,
    const int* __restrict__ bucket,
    unsigned short* __restrict__ OutA,
    unsigned short* __restrict__ OutB)
{
  constexpr int BM = 256, BN = 256;
  constexpr int KDIM = (LAYER == 1) ? D_DIM : F_DIM;
  constexpr int NDIM = (LAYER == 1) ? F_DIM : D_DIM;
  constexpr int KSPAN = (LAYER == 1) ? KDIM : (KDIM / 2);  // per-block K range
  constexpr int HALVES = KSPAN / 32;                       // 32 or 64

  const int q = gridDim.x >> 3;
  const int g = (blockIdx.x & 7) * q + (blockIdx.x >> 3);
  const int cc = g / MAXT;                 // L1: ntile; L2: (ntile<<1)|split
  const int mt = g % MAXT;
  if (mt >= toff[NE]) return;
  int e = 0;
  while (mt >= toff[e + 1]) ++e;
  const int mtile = mt - toff[e];
  const int cnt_e = cnt[e];
  const int eoff = expoff[e];
  const int ntile = (LAYER == 1) ? cc : (cc >> 1);
  const int split = (LAYER == 1) ? 0 : (cc & 1);
  const int kbase = split * KSPAN;

  __shared__ __align__(16) char Alds[2 * 16384];   // 32 KiB ring-2
  __shared__ __align__(16) char Blds[2 * 16384];   // 32 KiB ring-2
  __shared__ int rowpair[BM];

  const int tid = threadIdx.x;
  const int lane = tid & 63;
  const int l15 = lane & 15, lhi = lane >> 4;
  const int wid = tid >> 6;
  const int uw = __builtin_amdgcn_readfirstlane(wid);
  const int wm = wid >> 2, wn = wid & 3;           // 4M x 4N waves

  if (LAYER == 1) {
    if (tid < BM) {
      int pos = mtile * BM + tid;
      rowpair[tid] = (pos < cnt_e) ? bucket[e * CAP + pos] : -1;
    }
    __syncthreads();
  }

  // staging: half = 1024 chunks of 16 B; thread owns chunk ci = tid for each
  // operand; r = ci>>2, c = ci&3; source chunk sc = c ^ ((r>>1)&3) (inverse
  // swizzle) so linear DMA dest (uw*1024 + lane*16) == swizzled read image.
  const unsigned short* a_src;
  const unsigned short* b_src;
  {
    int ci = tid;
    int r = ci >> 2, c = ci & 3;
    int sc = c ^ ((r >> 1) & 3);
    size_t arow;
    if (LAYER == 1) {
      int pair = rowpair[r];
      arow = (pair < 0) ? 0 : (size_t)(pair >> 1);
    } else {
      arow = (size_t)(eoff + mtile * BM + r);      // contiguous slot rows
    }
    a_src = Abase + arow * KDIM + kbase + sc * 8;
    b_src = Bt + (size_t)e * NDIM * KDIM +
            (size_t)(ntile * BN + r) * KDIM + kbase + sc * 8;
  }

  auto stage = [&](int h) {
    const int s = h & 1;
    gload(a_src + h * 32, &Alds[0] + s * 16384 + uw * 1024);
    gload(b_src + h * 32, &Blds[0] + s * 16384 + uw * 1024);
  };

  f32x4 acc[4][4];
#pragma unroll
  for (int m = 0; m < 4; ++m)
#pragma unroll
    for (int n = 0; n < 4; ++n) acc[m][n] = (f32x4){0.f, 0.f, 0.f, 0.f};

  stage(0);
  asm volatile("s_waitcnt vmcnt(0)" ::: "memory");
  __builtin_amdgcn_sched_barrier(0);
  __builtin_amdgcn_s_barrier();

  for (int H = 0; H < HALVES; ++H) {
    const char* aSlot = &Alds[0] + (H & 1) * 16384;
    const char* bSlot = &Blds[0] + (H & 1) * 16384;
    short8 bfr[4], af[4];
#pragma unroll
    for (int n = 0; n < 4; ++n) {
      const int row = wn * 64 + n * 16 + l15;
      bfr[n] = *(const short8*)(bSlot + row * 64 + ((lhi ^ ((row >> 1) & 3)) << 4));
    }
#pragma unroll
    for (int m = 0; m < 4; ++m) {
      const int row = wm * 64 + m * 16 + l15;
      af[m] = *(const short8*)(aSlot + row * 64 + ((lhi ^ ((row >> 1) & 3)) << 4));
    }
    if (H + 1 < HALVES) stage(H + 1);      // other slot; its reads done at H-1
    asm volatile("s_waitcnt lgkmcnt(0)" ::: "memory");
    __builtin_amdgcn_sched_barrier(0);
    __builtin_amdgcn_s_setprio(1);
#pragma unroll
    for (int m = 0; m < 4; ++m)
#pragma unroll
      for (int n = 0; n < 4; ++n)
        acc[m][n] = __builtin_amdgcn_mfma_f32_16x16x32_bf16(af[m], bfr[n], acc[m][n], 0, 0, 0);
    __builtin_amdgcn_s_setprio(0);
    if (H + 1 < HALVES) {
      asm volatile("s_waitcnt vmcnt(0)" ::: "memory");   // next slot landed
      __builtin_amdgcn_sched_barrier(0);
      __builtin_amdgcn_s_barrier();                      // all waves agree
    }
  }

  // epilogue: C/D layout col = lane&15, row = (lane>>4)*4 + j
#pragma unroll
  for (int m = 0; m < 4; ++m) {
#pragma unroll
    for (int j = 0; j < 4; ++j) {
      const int row = wm * 64 + m * 16 + lhi * 4 + j;
      if (mtile * BM + row >= cnt_e) continue;
      const size_t slot = (size_t)(eoff + mtile * BM + row);
#pragma unroll
      for (int n = 0; n < 4; ++n) {
        const int col = ntile * BN + wn * 64 + n * 16 + l15;
        if (LAYER == 1) {
          float val = acc[m][n][j] + bias[e * NDIM + col];
          float gl = 0.5f * val * (1.f + erff(val * 0.70710678118654752f));
          OutA[slot * F_DIM + col] = (unsigned short)f2bf(gl);
        } else {
          float val = acc[m][n][j] + (split == 0 ? bias[e * NDIM + col] : 0.f);
          unsigned short* dst = (split == 0) ? OutA : OutB;
          dst[slot * D_DIM + col] = (unsigned short)f2bf(val);
        }
      }
    }
  }
}

// ---------------- combine: out[t] = w0*(yA+yB)[s0] + w1*(yA+yB)[s1] ---------
__global__ __launch_bounds__(256) void combine_kernel(
    const unsigned short* __restrict__ ybufA, const unsigned short* __restrict__ ybufB,
    const float* __restrict__ pairw, const int* __restrict__ pairslot,
    float* __restrict__ out)
{
  const int t = blockIdx.x;
  const int tid = threadIdx.x;
  const float w0 = pairw[t * 2], w1 = pairw[t * 2 + 1];
  const int s0 = pairslot[t * 2], s1 = pairslot[t * 2 + 1];
  const short4v a0 = ((const short4v*)(ybufA + (size_t)s0 * D_DIM))[tid];
  const short4v b0 = ((const short4v*)(ybufB + (size_t)s0 * D_DIM))[tid];
  const short4v a1 = ((const short4v*)(ybufA + (size_t)s1 * D_DIM))[tid];
  const short4v b1 = ((const short4v*)(ybufB + (size_t)s1 * D_DIM))[tid];
  float4 o;
  o.x = w0 * (bf2f(a0.x) + bf2f(b0.x)) + w1 * (bf2f(a1.x) + bf2f(b1.x));
  o.y = w0 * (bf2f(a0.y) + bf2f(b0.y)) + w1 * (bf2f(a1.y) + bf2f(b1.y));
  o.z = w0 * (bf2f(a0.z) + bf2f(b0.z)) + w1 * (bf2f(a1.z) + bf2f(b1.z));
  o.w = w0 * (bf2f(a0.w) + bf2f(b0.w)) + w1 * (bf2f(a1.w) + bf2f(b1.w));
  ((float4*)(out + (size_t)t * D_DIM))[tid] = o;
}

// ---------------- launch ----------------------------------------------------
extern "C" void kernel_launch(void* const* d_in, const int* in_sizes, int n_in,
                              void* d_out, int out_size, void* d_ws, size_t ws_size,
                              hipStream_t stream)
{
  const float* X  = (const float*)d_in[0];
  const float* Wg = (const float*)d_in[1];
  const float* bg = (const float*)d_in[2];
  const float* W1 = (const float*)d_in[3];
  const float* b1 = (const float*)d_in[4];
  const float* W2 = (const float*)d_in[5];
  const float* b2 = (const float*)d_in[6];
  float* out = (float*)d_out;

  char* ws = (char*)d_ws;
  size_t off = 0;
  auto alloc = [&](size_t sz) {
    size_t o = off;
    off = (off + sz + 255) & ~(size_t)255;
    return o;
  };
  int*            cnt      = (int*)(ws + alloc(NE * sizeof(int)));
  int*            expoff   = (int*)(ws + alloc(NE * sizeof(int)));
  int*            toff     = (int*)(ws + alloc((NE + 1) * sizeof(int)));
  int*            bucket   = (int*)(ws + alloc((size_t)NE * CAP * sizeof(int)));
  float*          pairw    = (float*)(ws + alloc((size_t)N_TOK * 2 * sizeof(float)));
  int*            pairslot = (int*)(ws + alloc((size_t)N_TOK * 2 * sizeof(int)));
  unsigned short* Xb       = (unsigned short*)(ws + alloc((size_t)N_TOK * D_DIM * 2));
  unsigned short* W1t      = (unsigned short*)(ws + alloc((size_t)NE * D_DIM * F_DIM * 2));
  unsigned short* W2t      = (unsigned short*)(ws + alloc((size_t)NE * D_DIM * F_DIM * 2));
  unsigned short* hmid     = (unsigned short*)(ws + alloc((size_t)(N_TOK * 2 + 256) * F_DIM * 2));
  unsigned short* ybufB    = (unsigned short*)(ws + alloc((size_t)(N_TOK * 2 + 256) * D_DIM * 2));
  unsigned short* ybufA    = W1t;   // W1t dead after GEMM1

  hipMemsetAsync(cnt, 0, NE * sizeof(int), stream);

  gate_kernel<<<N_TOK, 256, 0, stream>>>(X, Wg, bg, cnt, bucket, pairw, Xb);
  transpose_both_kernel<<<dim3(64, 16, 2 * NE), 256, 0, stream>>>(W1, W2, W1t, W2t);
  prefix_fill_kernel<<<1, 256, 0, stream>>>(cnt, expoff, toff, bucket, pairslot);

  moe_gemm<1><<<MAXT * (F_DIM / 256), 1024, 0, stream>>>(   // 1152 blocks (%8==0)
      Xb, W1t, b1, cnt, expoff, toff, bucket, hmid, nullptr);
  moe_gemm<2><<<MAXT * (D_DIM / 256) * 2, 1024, 0, stream>>>( // 576 blocks (%8==0)
      hmid, W2t, b2, cnt, expoff, toff, bucket, ybufA, ybufB);
  combine_kernel<<<N_TOK, 256, 0, stream>>>(ybufA, ybufB, pairw, pairslot, out);
}

// Round 20
// 712.340 us; speedup vs baseline: 7.4716x; 7.4716x over previous
//
#include <hip/hip_runtime.h>
#include <hip/hip_bf16.h>
#include <cstdint>
#include <math.h>

#define N_TOK 8192
#define D_DIM 1024
#define F_DIM 4096
#define NE 8
#define CAP 8192
#define MAXT 72    // max sum_e ceil(cnt_e/256) = 71, padded

typedef __attribute__((ext_vector_type(8))) short short8;
typedef __attribute__((ext_vector_type(4))) short short4v;
typedef __attribute__((ext_vector_type(4))) float f32x4;

__device__ __forceinline__ short f2bf(float f) {
  __bf16 b = (__bf16)f;
  return *(short*)&b;
}
__device__ __forceinline__ float bf2f(short u) {
  union { unsigned int i; float f; } c;
  c.i = ((unsigned int)(unsigned short)u) << 16;
  return c.f;
}
__device__ __forceinline__ void gload(const void* g, void* l) {
  __builtin_amdgcn_global_load_lds(
      (const __attribute__((address_space(1))) uint32_t*)g,
      (__attribute__((address_space(3))) uint32_t*)l, 16, 0, 0);
}

// ---------------- fused pre-pass: gate (+X->bf16) AND weight transposes -----
// blocks 0..N_TOK-1: gating for one token.  blocks >= N_TOK: one 64x64
// transpose tile (W1 z<NE, W2 z>=NE). Independent work, one launch.
// Transpose LDS pad 68->65 + scalar access: bank = (4cx + j + ry + 16i)%32,
// exactly 2 lanes/bank (free) vs the old 8-way scalar-write conflict.
__global__ __launch_bounds__(256) void prepass_kernel(
    const float* __restrict__ X, const float* __restrict__ Wg,
    const float* __restrict__ bg, int* __restrict__ cnt,
    int* __restrict__ bucket, float* __restrict__ pairw,
    unsigned short* __restrict__ Xb,
    const float* __restrict__ W1, const float* __restrict__ W2,
    unsigned short* __restrict__ W1t, unsigned short* __restrict__ W2t)
{
  const int tid = threadIdx.x;
  if (blockIdx.x < N_TOK) {
    // ---- gate ----
    const int token = blockIdx.x;
    const float4* x4 = (const float4*)(X + (size_t)token * D_DIM);
    const float4* wg4 = (const float4*)Wg;
    float part[NE];
#pragma unroll
    for (int e = 0; e < NE; ++e) part[e] = 0.f;
    const float4 xv = x4[tid];
#pragma unroll
    for (int e = 0; e < NE; ++e) {
      const float4 wv = wg4[e * (D_DIM / 4) + tid];
      part[e] = fmaf(xv.x, wv.x, fmaf(xv.y, wv.y, fmaf(xv.z, wv.z, fmaf(xv.w, wv.w, part[e]))));
    }
    short4v o;
    o.x = f2bf(xv.x); o.y = f2bf(xv.y); o.z = f2bf(xv.z); o.w = f2bf(xv.w);
    ((short4v*)(Xb + (size_t)token * D_DIM))[tid] = o;

#pragma unroll
    for (int e = 0; e < NE; ++e) {
#pragma unroll
      for (int off = 32; off > 0; off >>= 1) part[e] += __shfl_down(part[e], off);
    }
    __shared__ float wsum[4][NE];
    const int wave = tid >> 6;
    if ((tid & 63) == 0) {
#pragma unroll
      for (int e = 0; e < NE; ++e) wsum[wave][e] = part[e];
    }
    __syncthreads();
    if (tid == 0) {
      float lg[NE];
#pragma unroll
      for (int e = 0; e < NE; ++e)
        lg[e] = wsum[0][e] + wsum[1][e] + wsum[2][e] + wsum[3][e] + bg[e];
      int e0 = 0;
#pragma unroll
      for (int e = 1; e < NE; ++e) if (lg[e] > lg[e0]) e0 = e;   // jax tie-break: lower idx
      int e1 = (e0 == 0) ? 1 : 0;
#pragma unroll
      for (int e = 0; e < NE; ++e) if (e != e0 && lg[e] > lg[e1]) e1 = e;
      float p1 = expf(lg[e1] - lg[e0]);          // p0 = 1; softmax denom cancels
      float inv = 1.f / (1.f + p1);
      pairw[token * 2]     = inv;
      pairw[token * 2 + 1] = p1 * inv;
      int pos0 = atomicAdd(&cnt[e0], 1);
      bucket[e0 * CAP + pos0] = token * 2;
      int pos1 = atomicAdd(&cnt[e1], 1);
      bucket[e1 * CAP + pos1] = token * 2 + 1;
    }
  } else {
    // ---- transpose tile ----
    __shared__ float tileT[64][65];
    const int idx = blockIdx.x - N_TOK;
    const int bx = idx & 63;
    const int by = (idx >> 6) & 15;
    const int z = idx >> 10;                 // 0..2*NE-1
    const bool is1 = (z < NE);
    const int ez = is1 ? z : z - NE;
    const int R = is1 ? D_DIM : F_DIM;
    const int C = is1 ? F_DIM : D_DIM;
    const float* src = (is1 ? W1 : W2) + (size_t)ez * D_DIM * F_DIM;
    unsigned short* dst = (is1 ? W1t : W2t) + (size_t)ez * D_DIM * F_DIM;
    const int c0 = (is1 ? bx : by) * 64;
    const int r0 = (is1 ? by : bx) * 64;
    const int cx = tid & 15;
    const int ry = tid >> 4;
#pragma unroll
    for (int i = 0; i < 4; ++i) {
      const int row = ry + i * 16;
      const float4 v = *(const float4*)(src + (size_t)(r0 + row) * C + c0 + cx * 4);
      tileT[cx * 4 + 0][row] = v.x;
      tileT[cx * 4 + 1][row] = v.y;
      tileT[cx * 4 + 2][row] = v.z;
      tileT[cx * 4 + 3][row] = v.w;
    }
    __syncthreads();
#pragma unroll
    for (int i = 0; i < 4; ++i) {
      const int cc = ry + i * 16;
      short4v o;
      o.x = f2bf(tileT[cc][cx * 4 + 0]);
      o.y = f2bf(tileT[cc][cx * 4 + 1]);
      o.z = f2bf(tileT[cc][cx * 4 + 2]);
      o.w = f2bf(tileT[cc][cx * 4 + 3]);
      *(short4v*)(dst + (size_t)(c0 + cc) * R + r0 + cx * 4) = o;
    }
  }
}

// ---------------- prefix sums + pair->slot map (one launch) -----------------
__global__ __launch_bounds__(256) void prefix_fill_kernel(
    const int* __restrict__ cnt, int* __restrict__ expoff,
    int* __restrict__ toff, const int* __restrict__ bucket,
    int* __restrict__ pairslot)
{
  __shared__ int soff[NE];
  if (threadIdx.x == 0) {
    int s = 0, t = 0;
#pragma unroll
    for (int e = 0; e < NE; ++e) {
      expoff[e] = s; soff[e] = s;
      toff[e] = t;
      s += cnt[e];
      t += (cnt[e] + 255) >> 8;
    }
    toff[NE] = t;
  }
  __syncthreads();
  for (int e = 0; e < NE; ++e) {
    const int n = cnt[e], off = soff[e];
    for (int p = threadIdx.x; p < n; p += 256)
      pairslot[bucket[e * CAP + p]] = off + p;
  }
}

// ---------------- grouped expert GEMM: 256x256, 16 waves, ring-4 ------------
// R18 core (224 us, VGPR 64, 0 conflicts) with flight deepened one notch:
// ring-4 K=32 half slots (132 KB LDS, still 1 block/CU like R18). Per half H:
// vmcnt(4) [H landed; H+1,H+2 in flight] + barrier -> read frags (8 ds_read/
// wave) -> stage(H+3) (2 insts/thread; refills slot (H-1)&3, whose reads
// completed before H's barrier) -> lgkmcnt(0) -> setprio + 16 MFMA.
// Tail: vmcnt 4 -> 2 -> 0. Swizzle c^((r>>1)&3) (R15/R18-proven, 0 conflict).
template<int LAYER>
__global__ __launch_bounds__(1024, 4) void moe_gemm(
    const unsigned short* __restrict__ Abase,
    const unsigned short* __restrict__ Bt,
    const float* __restrict__ bias,
    const int* __restrict__ cnt,
    const int* __restrict__ expoff,
    const int* __restrict__ toff,
    const int* __restrict__ bucket,
    unsigned short* __restrict__ OutA,
    unsigned short* __restrict__ OutB)
{
  constexpr int BM = 256, BN = 256;
  constexpr int KDIM = (LAYER == 1) ? D_DIM : F_DIM;
  constexpr int NDIM = (LAYER == 1) ? F_DIM : D_DIM;
  constexpr int KSPAN = (LAYER == 1) ? KDIM : (KDIM / 2);  // per-block K range
  constexpr int HALVES = KSPAN / 32;                       // 32 or 64

  const int q = gridDim.x >> 3;
  const int g = (blockIdx.x & 7) * q + (blockIdx.x >> 3);
  const int cc = g / MAXT;                 // L1: ntile; L2: (ntile<<1)|split
  const int mt = g % MAXT;
  if (mt >= toff[NE]) return;
  int e = 0;
  while (mt >= toff[e + 1]) ++e;
  const int mtile = mt - toff[e];
  const int cnt_e = cnt[e];
  const int eoff = expoff[e];
  const int ntile = (LAYER == 1) ? cc : (cc >> 1);
  const int split = (LAYER == 1) ? 0 : (cc & 1);
  const int kbase = split * KSPAN;

  __shared__ __align__(16) char Alds[4 * 16384];   // 64 KiB ring-4
  __shared__ __align__(16) char Blds[4 * 16384];   // 64 KiB ring-4
  __shared__ int rowpair[BM];

  const int tid = threadIdx.x;
  const int lane = tid & 63;
  const int l15 = lane & 15, lhi = lane >> 4;
  const int wid = tid >> 6;
  const int uw = __builtin_amdgcn_readfirstlane(wid);
  const int wm = wid >> 2, wn = wid & 3;           // 4M x 4N waves

  if (LAYER == 1) {
    if (tid < BM) {
      int pos = mtile * BM + tid;
      rowpair[tid] = (pos < cnt_e) ? bucket[e * CAP + pos] : -1;
    }
    __syncthreads();
  }

  // staging: half = 1024 chunks of 16 B; thread owns chunk ci = tid for each
  // operand; r = ci>>2, c = ci&3; source chunk sc = c ^ ((r>>1)&3) (inverse
  // swizzle) so linear DMA dest (uw*1024 + lane*16) == swizzled read image.
  const unsigned short* a_src;
  const unsigned short* b_src;
  {
    int ci = tid;
    int r = ci >> 2, c = ci & 3;
    int sc = c ^ ((r >> 1) & 3);
    size_t arow;
    if (LAYER == 1) {
      int pair = rowpair[r];
      arow = (pair < 0) ? 0 : (size_t)(pair >> 1);
    } else {
      arow = (size_t)(eoff + mtile * BM + r);      // contiguous slot rows
    }
    a_src = Abase + arow * KDIM + kbase + sc * 8;
    b_src = Bt + (size_t)e * NDIM * KDIM +
            (size_t)(ntile * BN + r) * KDIM + kbase + sc * 8;
  }

  auto stage = [&](int h) {
    const int s = h & 3;
    gload(a_src + h * 32, &Alds[0] + s * 16384 + uw * 1024);
    gload(b_src + h * 32, &Blds[0] + s * 16384 + uw * 1024);
  };

  f32x4 acc[4][4];
#pragma unroll
  for (int m = 0; m < 4; ++m)
#pragma unroll
    for (int n = 0; n < 4; ++n) acc[m][n] = (f32x4){0.f, 0.f, 0.f, 0.f};

  stage(0); stage(1); stage(2);            // 6 insts/thread outstanding

  for (int H = 0; H < HALVES; ++H) {
    if (H + 2 < HALVES)      asm volatile("s_waitcnt vmcnt(4)" ::: "memory");
    else if (H + 1 < HALVES) asm volatile("s_waitcnt vmcnt(2)" ::: "memory");
    else                     asm volatile("s_waitcnt vmcnt(0)" ::: "memory");
    __builtin_amdgcn_sched_barrier(0);
    __builtin_amdgcn_s_barrier();

    const char* aSlot = &Alds[0] + (H & 3) * 16384;
    const char* bSlot = &Blds[0] + (H & 3) * 16384;
    short8 bfr[4], af[4];
#pragma unroll
    for (int n = 0; n < 4; ++n) {
      const int row = wn * 64 + n * 16 + l15;
      bfr[n] = *(const short8*)(bSlot + row * 64 + ((lhi ^ ((row >> 1) & 3)) << 4));
    }
#pragma unroll
    for (int m = 0; m < 4; ++m) {
      const int row = wm * 64 + m * 16 + l15;
      af[m] = *(const short8*)(aSlot + row * 64 + ((lhi ^ ((row >> 1) & 3)) << 4));
    }
    if (H + 3 < HALVES) stage(H + 3);      // refills slot (H-1)&3
    asm volatile("s_waitcnt lgkmcnt(0)" ::: "memory");
    __builtin_amdgcn_sched_barrier(0);
    __builtin_amdgcn_s_setprio(1);
#pragma unroll
    for (int m = 0; m < 4; ++m)
#pragma unroll
      for (int n = 0; n < 4; ++n)
        acc[m][n] = __builtin_amdgcn_mfma_f32_16x16x32_bf16(af[m], bfr[n], acc[m][n], 0, 0, 0);
    __builtin_amdgcn_s_setprio(0);
  }

  // epilogue: C/D layout col = lane&15, row = (lane>>4)*4 + j
#pragma unroll
  for (int m = 0; m < 4; ++m) {
#pragma unroll
    for (int j = 0; j < 4; ++j) {
      const int row = wm * 64 + m * 16 + lhi * 4 + j;
      if (mtile * BM + row >= cnt_e) continue;
      const size_t slot = (size_t)(eoff + mtile * BM + row);
#pragma unroll
      for (int n = 0; n < 4; ++n) {
        const int col = ntile * BN + wn * 64 + n * 16 + l15;
        if (LAYER == 1) {
          float val = acc[m][n][j] + bias[e * NDIM + col];
          float gl = 0.5f * val * (1.f + erff(val * 0.70710678118654752f));
          OutA[slot * F_DIM + col] = (unsigned short)f2bf(gl);
        } else {
          float val = acc[m][n][j] + (split == 0 ? bias[e * NDIM + col] : 0.f);
          unsigned short* dst = (split == 0) ? OutA : OutB;
          dst[slot * D_DIM + col] = (unsigned short)f2bf(val);
        }
      }
    }
  }
}

// ---------------- combine: out[t] = w0*(yA+yB)[s0] + w1*(yA+yB)[s1] ---------
__global__ __launch_bounds__(256) void combine_kernel(
    const unsigned short* __restrict__ ybufA, const unsigned short* __restrict__ ybufB,
    const float* __restrict__ pairw, const int* __restrict__ pairslot,
    float* __restrict__ out)
{
  const int t = blockIdx.x;
  const int tid = threadIdx.x;
  const float w0 = pairw[t * 2], w1 = pairw[t * 2 + 1];
  const int s0 = pairslot[t * 2], s1 = pairslot[t * 2 + 1];
  const short4v a0 = ((const short4v*)(ybufA + (size_t)s0 * D_DIM))[tid];
  const short4v b0 = ((const short4v*)(ybufB + (size_t)s0 * D_DIM))[tid];
  const short4v a1 = ((const short4v*)(ybufA + (size_t)s1 * D_DIM))[tid];
  const short4v b1 = ((const short4v*)(ybufB + (size_t)s1 * D_DIM))[tid];
  float4 o;
  o.x = w0 * (bf2f(a0.x) + bf2f(b0.x)) + w1 * (bf2f(a1.x) + bf2f(b1.x));
  o.y = w0 * (bf2f(a0.y) + bf2f(b0.y)) + w1 * (bf2f(a1.y) + bf2f(b1.y));
  o.z = w0 * (bf2f(a0.z) + bf2f(b0.z)) + w1 * (bf2f(a1.z) + bf2f(b1.z));
  o.w = w0 * (bf2f(a0.w) + bf2f(b0.w)) + w1 * (bf2f(a1.w) + bf2f(b1.w));
  ((float4*)(out + (size_t)t * D_DIM))[tid] = o;
}

// ---------------- launch ----------------------------------------------------
extern "C" void kernel_launch(void* const* d_in, const int* in_sizes, int n_in,
                              void* d_out, int out_size, void* d_ws, size_t ws_size,
                              hipStream_t stream)
{
  const float* X  = (const float*)d_in[0];
  const float* Wg = (const float*)d_in[1];
  const float* bg = (const float*)d_in[2];
  const float* W1 = (const float*)d_in[3];
  const float* b1 = (const float*)d_in[4];
  const float* W2 = (const float*)d_in[5];
  const float* b2 = (const float*)d_in[6];
  float* out = (float*)d_out;

  char* ws = (char*)d_ws;
  size_t off = 0;
  auto alloc = [&](size_t sz) {
    size_t o = off;
    off = (off + sz + 255) & ~(size_t)255;
    return o;
  };
  int*            cnt      = (int*)(ws + alloc(NE * sizeof(int)));
  int*            expoff   = (int*)(ws + alloc(NE * sizeof(int)));
  int*            toff     = (int*)(ws + alloc((NE + 1) * sizeof(int)));
  int*            bucket   = (int*)(ws + alloc((size_t)NE * CAP * sizeof(int)));
  float*          pairw    = (float*)(ws + alloc((size_t)N_TOK * 2 * sizeof(float)));
  int*            pairslot = (int*)(ws + alloc((size_t)N_TOK * 2 * sizeof(int)));
  unsigned short* Xb       = (unsigned short*)(ws + alloc((size_t)N_TOK * D_DIM * 2));
  unsigned short* W1t      = (unsigned short*)(ws + alloc((size_t)NE * D_DIM * F_DIM * 2));
  unsigned short* W2t      = (unsigned short*)(ws + alloc((size_t)NE * D_DIM * F_DIM * 2));
  unsigned short* hmid     = (unsigned short*)(ws + alloc((size_t)(N_TOK * 2 + 256) * F_DIM * 2));
  unsigned short* ybufB    = (unsigned short*)(ws + alloc((size_t)(N_TOK * 2 + 256) * D_DIM * 2));
  unsigned short* ybufA    = W1t;   // W1t dead after GEMM1

  hipMemsetAsync(cnt, 0, NE * sizeof(int), stream);

  prepass_kernel<<<N_TOK + 2 * NE * 1024, 256, 0, stream>>>(
      X, Wg, bg, cnt, bucket, pairw, Xb, W1, W2, W1t, W2t);
  prefix_fill_kernel<<<1, 256, 0, stream>>>(cnt, expoff, toff, bucket, pairslot);

  moe_gemm<1><<<MAXT * (F_DIM / 256), 1024, 0, stream>>>(   // 1152 blocks (%8==0)
      Xb, W1t, b1, cnt, expoff, toff, bucket, hmid, nullptr);
  moe_gemm<2><<<MAXT * (D_DIM / 256) * 2, 1024, 0, stream>>>( // 576 blocks (%8==0)
      hmid, W2t, b2, cnt, expoff, toff, bucket, ybufA, ybufB);
  combine_kernel<<<N_TOK, 256, 0, stream>>>(ybufA, ybufB, pairw, pairslot, out);
}

// Round 21
// 691.478 us; speedup vs baseline: 7.6970x; 1.0302x over previous
//
#include <hip/hip_runtime.h>
#include <hip/hip_bf16.h>
#include <cstdint>
#include <math.h>

#define N_TOK 8192
#define D_DIM 1024
#define F_DIM 4096
#define NE 8
#define CAP 8192
#define MAXT 72    // max sum_e ceil(cnt_e/256) = 71, padded

typedef __attribute__((ext_vector_type(8))) short short8;
typedef __attribute__((ext_vector_type(4))) short short4v;
typedef __attribute__((ext_vector_type(4))) float f32x4;

__device__ __forceinline__ short f2bf(float f) {
  __bf16 b = (__bf16)f;
  return *(short*)&b;
}
__device__ __forceinline__ float bf2f(short u) {
  union { unsigned int i; float f; } c;
  c.i = ((unsigned int)(unsigned short)u) << 16;
  return c.f;
}
__device__ __forceinline__ void gload(const void* g, void* l) {
  __builtin_amdgcn_global_load_lds(
      (const __attribute__((address_space(1))) uint32_t*)g,
      (__attribute__((address_space(3))) uint32_t*)l, 16, 0, 0);
}

// ---------------- prepass: gate (+X->bf16) AND W1 transpose -----------------
// blocks 0..N_TOK-1: gating. blocks >= N_TOK: one 64x64 W1 transpose tile.
// (W2's transpose rides inside GEMM1's dispatch -- see moe_gemm<1>.)
__global__ __launch_bounds__(256) void prepass_kernel(
    const float* __restrict__ X, const float* __restrict__ Wg,
    const float* __restrict__ bg, int* __restrict__ cnt,
    int* __restrict__ bucket, float* __restrict__ pairw,
    unsigned short* __restrict__ Xb,
    const float* __restrict__ W1, unsigned short* __restrict__ W1t)
{
  const int tid = threadIdx.x;
  if (blockIdx.x < N_TOK) {
    // ---- gate ----
    const int token = blockIdx.x;
    const float4* x4 = (const float4*)(X + (size_t)token * D_DIM);
    const float4* wg4 = (const float4*)Wg;
    float part[NE];
#pragma unroll
    for (int e = 0; e < NE; ++e) part[e] = 0.f;
    const float4 xv = x4[tid];
#pragma unroll
    for (int e = 0; e < NE; ++e) {
      const float4 wv = wg4[e * (D_DIM / 4) + tid];
      part[e] = fmaf(xv.x, wv.x, fmaf(xv.y, wv.y, fmaf(xv.z, wv.z, fmaf(xv.w, wv.w, part[e]))));
    }
    short4v o;
    o.x = f2bf(xv.x); o.y = f2bf(xv.y); o.z = f2bf(xv.z); o.w = f2bf(xv.w);
    ((short4v*)(Xb + (size_t)token * D_DIM))[tid] = o;

#pragma unroll
    for (int e = 0; e < NE; ++e) {
#pragma unroll
      for (int off = 32; off > 0; off >>= 1) part[e] += __shfl_down(part[e], off);
    }
    __shared__ float wsum[4][NE];
    const int wave = tid >> 6;
    if ((tid & 63) == 0) {
#pragma unroll
      for (int e = 0; e < NE; ++e) wsum[wave][e] = part[e];
    }
    __syncthreads();
    if (tid == 0) {
      float lg[NE];
#pragma unroll
      for (int e = 0; e < NE; ++e)
        lg[e] = wsum[0][e] + wsum[1][e] + wsum[2][e] + wsum[3][e] + bg[e];
      int e0 = 0;
#pragma unroll
      for (int e = 1; e < NE; ++e) if (lg[e] > lg[e0]) e0 = e;   // jax tie-break: lower idx
      int e1 = (e0 == 0) ? 1 : 0;
#pragma unroll
      for (int e = 0; e < NE; ++e) if (e != e0 && lg[e] > lg[e1]) e1 = e;
      float p1 = expf(lg[e1] - lg[e0]);          // p0 = 1; softmax denom cancels
      float inv = 1.f / (1.f + p1);
      pairw[token * 2]     = inv;
      pairw[token * 2 + 1] = p1 * inv;
      int pos0 = atomicAdd(&cnt[e0], 1);
      bucket[e0 * CAP + pos0] = token * 2;
      int pos1 = atomicAdd(&cnt[e1], 1);
      bucket[e1 * CAP + pos1] = token * 2 + 1;
    }
  } else {
    // ---- W1 transpose tile: src D x F (R=1024,C=4096) -> W1t [F][D] -------
    __shared__ float tileT[64][65];
    const int idx = blockIdx.x - N_TOK;          // 0..8191
    const int bx = idx & 63;                     // c-tile (F)
    const int by = (idx >> 6) & 15;              // r-tile (D)
    const int ez = idx >> 10;
    const float* src = W1 + (size_t)ez * D_DIM * F_DIM;
    unsigned short* dst = W1t + (size_t)ez * D_DIM * F_DIM;
    const int c0 = bx * 64, r0 = by * 64;
    const int cx = tid & 15;
    const int ry = tid >> 4;
#pragma unroll
    for (int i = 0; i < 4; ++i) {
      const int row = ry + i * 16;
      const float4 v = *(const float4*)(src + (size_t)(r0 + row) * F_DIM + c0 + cx * 4);
      tileT[cx * 4 + 0][row] = v.x;
      tileT[cx * 4 + 1][row] = v.y;
      tileT[cx * 4 + 2][row] = v.z;
      tileT[cx * 4 + 3][row] = v.w;
    }
    __syncthreads();
#pragma unroll
    for (int i = 0; i < 4; ++i) {
      const int cc = ry + i * 16;
      short4v o;
      o.x = f2bf(tileT[cc][cx * 4 + 0]);
      o.y = f2bf(tileT[cc][cx * 4 + 1]);
      o.z = f2bf(tileT[cc][cx * 4 + 2]);
      o.w = f2bf(tileT[cc][cx * 4 + 3]);
      *(short4v*)(dst + (size_t)(c0 + cc) * D_DIM + r0 + cx * 4) = o;
    }
  }
}

// ---------------- prefix sums + pair->slot map (one launch) -----------------
__global__ __launch_bounds__(256) void prefix_fill_kernel(
    const int* __restrict__ cnt, int* __restrict__ expoff,
    int* __restrict__ toff, const int* __restrict__ bucket,
    int* __restrict__ pairslot)
{
  __shared__ int soff[NE];
  if (threadIdx.x == 0) {
    int s = 0, t = 0;
#pragma unroll
    for (int e = 0; e < NE; ++e) {
      expoff[e] = s; soff[e] = s;
      toff[e] = t;
      s += cnt[e];
      t += (cnt[e] + 255) >> 8;
    }
    toff[NE] = t;
  }
  __syncthreads();
  for (int e = 0; e < NE; ++e) {
    const int n = cnt[e], off = soff[e];
    for (int p = threadIdx.x; p < n; p += 256)
      pairslot[bucket[e * CAP + p]] = off + p;
  }
}

// ---------------- grouped expert GEMM: 256x256, 16 waves, ring-4 ------------
// R20 core unchanged (ring-4 K=32 halves, vmcnt(4) flight, swizzle
// c^((r>>1)&3), 0 conflicts, VGPR 64, 1 block/CU).
// LAYER 1 ONLY: blocks bid >= NG are W2-TRANSPOSE workers (256 blocks x
// 4 groups x 8 tiles of 64x64) riding in this dispatch's tail; stream order
// guarantees W2t is complete before GEMM2 launches.
template<int LAYER>
__global__ __launch_bounds__(1024, 4) void moe_gemm(
    const unsigned short* __restrict__ Abase,
    const unsigned short* __restrict__ Bt,
    const float* __restrict__ bias,
    const int* __restrict__ cnt,
    const int* __restrict__ expoff,
    const int* __restrict__ toff,
    const int* __restrict__ bucket,
    unsigned short* __restrict__ OutA,
    unsigned short* __restrict__ OutB,
    const float* __restrict__ W2src,
    unsigned short* __restrict__ W2dst)
{
  constexpr int BM = 256, BN = 256;
  constexpr int KDIM = (LAYER == 1) ? D_DIM : F_DIM;
  constexpr int NDIM = (LAYER == 1) ? F_DIM : D_DIM;
  constexpr int KSPAN = (LAYER == 1) ? KDIM : (KDIM / 2);  // per-block K range
  constexpr int HALVES = KSPAN / 32;                       // 32 or 64
  constexpr int NG = (LAYER == 1) ? (MAXT * (F_DIM / 256))
                                  : (MAXT * (D_DIM / 256) * 2);  // GEMM blocks

  __shared__ __align__(16) char Alds[4 * 16384];   // 64 KiB ring-4
  __shared__ __align__(16) char Blds[4 * 16384];   // 64 KiB ring-4
  __shared__ int rowpair[BM];

  const int tid = threadIdx.x;

  if (LAYER == 1 && (int)blockIdx.x >= NG) {
    // ---- W2 transpose workers: src F x D (R=4096,C=1024) -> W2t [D][F] ----
    // 8192 tiles; 256 blocks x 4 groups(256thr) x 8 tiles. LDS: groups 0,1
    // use Alds, 2,3 use Blds (64x65 floats = 16.6 KB each, 20 KB spacing).
    const int wblk = blockIdx.x - NG;
    const int grp = tid >> 8;
    const int gt = tid & 255;
    float* tileT = (float*)((grp < 2 ? Alds : Blds) + (grp & 1) * 20480);
    const int cx = gt & 15;
    const int ry = gt >> 4;
    for (int it = 0; it < 8; ++it) {
      const int t = wblk * 32 + grp * 8 + it;
      const int ct = t & 15;                 // c-tile (D)
      const int rt = (t >> 4) & 63;          // r-tile (F)
      const int ez = t >> 10;
      const float* src = W2src + (size_t)ez * D_DIM * F_DIM;
      unsigned short* dst = W2dst + (size_t)ez * D_DIM * F_DIM;
      const int c0 = ct * 64, r0 = rt * 64;
#pragma unroll
      for (int i = 0; i < 4; ++i) {
        const int row = ry + i * 16;
        const float4 v = *(const float4*)(src + (size_t)(r0 + row) * D_DIM + c0 + cx * 4);
        tileT[(cx * 4 + 0) * 65 + row] = v.x;
        tileT[(cx * 4 + 1) * 65 + row] = v.y;
        tileT[(cx * 4 + 2) * 65 + row] = v.z;
        tileT[(cx * 4 + 3) * 65 + row] = v.w;
      }
      __syncthreads();
#pragma unroll
      for (int i = 0; i < 4; ++i) {
        const int cc = ry + i * 16;
        short4v o;
        o.x = f2bf(tileT[cc * 65 + cx * 4 + 0]);
        o.y = f2bf(tileT[cc * 65 + cx * 4 + 1]);
        o.z = f2bf(tileT[cc * 65 + cx * 4 + 2]);
        o.w = f2bf(tileT[cc * 65 + cx * 4 + 3]);
        *(short4v*)(dst + (size_t)(c0 + cc) * F_DIM + r0 + cx * 4) = o;
      }
      __syncthreads();
    }
    return;
  }

  // ---- GEMM path (R20-identical) ----
  const int q = NG >> 3;
  const int g = ((int)blockIdx.x & 7) * q + ((int)blockIdx.x >> 3);
  const int cc = g / MAXT;                 // L1: ntile; L2: (ntile<<1)|split
  const int mt = g % MAXT;
  if (mt >= toff[NE]) return;
  int e = 0;
  while (mt >= toff[e + 1]) ++e;
  const int mtile = mt - toff[e];
  const int cnt_e = cnt[e];
  const int eoff = expoff[e];
  const int ntile = (LAYER == 1) ? cc : (cc >> 1);
  const int split = (LAYER == 1) ? 0 : (cc & 1);
  const int kbase = split * KSPAN;

  const int lane = tid & 63;
  const int l15 = lane & 15, lhi = lane >> 4;
  const int wid = tid >> 6;
  const int uw = __builtin_amdgcn_readfirstlane(wid);
  const int wm = wid >> 2, wn = wid & 3;           // 4M x 4N waves

  if (LAYER == 1) {
    if (tid < BM) {
      int pos = mtile * BM + tid;
      rowpair[tid] = (pos < cnt_e) ? bucket[e * CAP + pos] : -1;
    }
    __syncthreads();
  }

  const unsigned short* a_src;
  const unsigned short* b_src;
  {
    int ci = tid;
    int r = ci >> 2, c = ci & 3;
    int sc = c ^ ((r >> 1) & 3);
    size_t arow;
    if (LAYER == 1) {
      int pair = rowpair[r];
      arow = (pair < 0) ? 0 : (size_t)(pair >> 1);
    } else {
      arow = (size_t)(eoff + mtile * BM + r);      // contiguous slot rows
    }
    a_src = Abase + arow * KDIM + kbase + sc * 8;
    b_src = Bt + (size_t)e * NDIM * KDIM +
            (size_t)(ntile * BN + r) * KDIM + kbase + sc * 8;
  }

  auto stage = [&](int h) {
    const int s = h & 3;
    gload(a_src + h * 32, &Alds[0] + s * 16384 + uw * 1024);
    gload(b_src + h * 32, &Blds[0] + s * 16384 + uw * 1024);
  };

  f32x4 acc[4][4];
#pragma unroll
  for (int m = 0; m < 4; ++m)
#pragma unroll
    for (int n = 0; n < 4; ++n) acc[m][n] = (f32x4){0.f, 0.f, 0.f, 0.f};

  stage(0); stage(1); stage(2);            // 6 insts/thread outstanding

  for (int H = 0; H < HALVES; ++H) {
    if (H + 2 < HALVES)      asm volatile("s_waitcnt vmcnt(4)" ::: "memory");
    else if (H + 1 < HALVES) asm volatile("s_waitcnt vmcnt(2)" ::: "memory");
    else                     asm volatile("s_waitcnt vmcnt(0)" ::: "memory");
    __builtin_amdgcn_sched_barrier(0);
    __builtin_amdgcn_s_barrier();

    const char* aSlot = &Alds[0] + (H & 3) * 16384;
    const char* bSlot = &Blds[0] + (H & 3) * 16384;
    short8 bfr[4], af[4];
#pragma unroll
    for (int n = 0; n < 4; ++n) {
      const int row = wn * 64 + n * 16 + l15;
      bfr[n] = *(const short8*)(bSlot + row * 64 + ((lhi ^ ((row >> 1) & 3)) << 4));
    }
#pragma unroll
    for (int m = 0; m < 4; ++m) {
      const int row = wm * 64 + m * 16 + l15;
      af[m] = *(const short8*)(aSlot + row * 64 + ((lhi ^ ((row >> 1) & 3)) << 4));
    }
    if (H + 3 < HALVES) stage(H + 3);      // refills slot (H-1)&3
    asm volatile("s_waitcnt lgkmcnt(0)" ::: "memory");
    __builtin_amdgcn_sched_barrier(0);
    __builtin_amdgcn_s_setprio(1);
#pragma unroll
    for (int m = 0; m < 4; ++m)
#pragma unroll
      for (int n = 0; n < 4; ++n)
        acc[m][n] = __builtin_amdgcn_mfma_f32_16x16x32_bf16(af[m], bfr[n], acc[m][n], 0, 0, 0);
    __builtin_amdgcn_s_setprio(0);
  }

  // epilogue: C/D layout col = lane&15, row = (lane>>4)*4 + j
#pragma unroll
  for (int m = 0; m < 4; ++m) {
#pragma unroll
    for (int j = 0; j < 4; ++j) {
      const int row = wm * 64 + m * 16 + lhi * 4 + j;
      if (mtile * BM + row >= cnt_e) continue;
      const size_t slot = (size_t)(eoff + mtile * BM + row);
#pragma unroll
      for (int n = 0; n < 4; ++n) {
        const int col = ntile * BN + wn * 64 + n * 16 + l15;
        if (LAYER == 1) {
          float val = acc[m][n][j] + bias[e * NDIM + col];
          float gl = 0.5f * val * (1.f + erff(val * 0.70710678118654752f));
          OutA[slot * F_DIM + col] = (unsigned short)f2bf(gl);
        } else {
          float val = acc[m][n][j] + (split == 0 ? bias[e * NDIM + col] : 0.f);
          unsigned short* dst = (split == 0) ? OutA : OutB;
          dst[slot * D_DIM + col] = (unsigned short)f2bf(val);
        }
      }
    }
  }
}

// ---------------- combine: out[t] = w0*(yA+yB)[s0] + w1*(yA+yB)[s1] ---------
__global__ __launch_bounds__(256) void combine_kernel(
    const unsigned short* __restrict__ ybufA, const unsigned short* __restrict__ ybufB,
    const float* __restrict__ pairw, const int* __restrict__ pairslot,
    float* __restrict__ out)
{
  const int t = blockIdx.x;
  const int tid = threadIdx.x;
  const float w0 = pairw[t * 2], w1 = pairw[t * 2 + 1];
  const int s0 = pairslot[t * 2], s1 = pairslot[t * 2 + 1];
  const short4v a0 = ((const short4v*)(ybufA + (size_t)s0 * D_DIM))[tid];
  const short4v b0 = ((const short4v*)(ybufB + (size_t)s0 * D_DIM))[tid];
  const short4v a1 = ((const short4v*)(ybufA + (size_t)s1 * D_DIM))[tid];
  const short4v b1 = ((const short4v*)(ybufB + (size_t)s1 * D_DIM))[tid];
  float4 o;
  o.x = w0 * (bf2f(a0.x) + bf2f(b0.x)) + w1 * (bf2f(a1.x) + bf2f(b1.x));
  o.y = w0 * (bf2f(a0.y) + bf2f(b0.y)) + w1 * (bf2f(a1.y) + bf2f(b1.y));
  o.z = w0 * (bf2f(a0.z) + bf2f(b0.z)) + w1 * (bf2f(a1.z) + bf2f(b1.z));
  o.w = w0 * (bf2f(a0.w) + bf2f(b0.w)) + w1 * (bf2f(a1.w) + bf2f(b1.w));
  ((float4*)(out + (size_t)t * D_DIM))[tid] = o;
}

// ---------------- launch ----------------------------------------------------
extern "C" void kernel_launch(void* const* d_in, const int* in_sizes, int n_in,
                              void* d_out, int out_size, void* d_ws, size_t ws_size,
                              hipStream_t stream)
{
  const float* X  = (const float*)d_in[0];
  const float* Wg = (const float*)d_in[1];
  const float* bg = (const float*)d_in[2];
  const float* W1 = (const float*)d_in[3];
  const float* b1 = (const float*)d_in[4];
  const float* W2 = (const float*)d_in[5];
  const float* b2 = (const float*)d_in[6];
  float* out = (float*)d_out;

  char* ws = (char*)d_ws;
  size_t off = 0;
  auto alloc = [&](size_t sz) {
    size_t o = off;
    off = (off + sz + 255) & ~(size_t)255;
    return o;
  };
  int*            cnt      = (int*)(ws + alloc(NE * sizeof(int)));
  int*            expoff   = (int*)(ws + alloc(NE * sizeof(int)));
  int*            toff     = (int*)(ws + alloc((NE + 1) * sizeof(int)));
  int*            bucket   = (int*)(ws + alloc((size_t)NE * CAP * sizeof(int)));
  float*          pairw    = (float*)(ws + alloc((size_t)N_TOK * 2 * sizeof(float)));
  int*            pairslot = (int*)(ws + alloc((size_t)N_TOK * 2 * sizeof(int)));
  unsigned short* Xb       = (unsigned short*)(ws + alloc((size_t)N_TOK * D_DIM * 2));
  unsigned short* W1t      = (unsigned short*)(ws + alloc((size_t)NE * D_DIM * F_DIM * 2));
  unsigned short* W2t      = (unsigned short*)(ws + alloc((size_t)NE * D_DIM * F_DIM * 2));
  unsigned short* hmid     = (unsigned short*)(ws + alloc((size_t)(N_TOK * 2 + 256) * F_DIM * 2));
  unsigned short* ybufB    = (unsigned short*)(ws + alloc((size_t)(N_TOK * 2 + 256) * D_DIM * 2));
  unsigned short* ybufA    = W1t;   // W1t dead after GEMM1

  hipMemsetAsync(cnt, 0, NE * sizeof(int), stream);

  prepass_kernel<<<N_TOK + NE * 1024, 256, 0, stream>>>(
      X, Wg, bg, cnt, bucket, pairw, Xb, W1, W1t);
  prefix_fill_kernel<<<1, 256, 0, stream>>>(cnt, expoff, toff, bucket, pairslot);

  moe_gemm<1><<<MAXT * (F_DIM / 256) + 256, 1024, 0, stream>>>(  // 1152 GEMM + 256 W2T
      Xb, W1t, b1, cnt, expoff, toff, bucket, hmid, nullptr, W2, W2t);
  moe_gemm<2><<<MAXT * (D_DIM / 256) * 2, 1024, 0, stream>>>(    // 576 blocks
      hmid, W2t, b2, cnt, expoff, toff, bucket, ybufA, ybufB, nullptr, nullptr);
  combine_kernel<<<N_TOK, 256, 0, stream>>>(ybufA, ybufB, pairw, pairslot, out);
}

// Round 22
// 555.552 us; speedup vs baseline: 9.5802x; 1.2447x over previous
//
#include <hip/hip_runtime.h>
#include <hip/hip_bf16.h>
#include <cstdint>
#include <math.h>

#define N_TOK 8192
#define D_DIM 1024
#define F_DIM 4096
#define NE 8
#define CAP 8192
#define MAXT 72    // max sum_e ceil(cnt_e/256) = 71, padded
#define TPB 32     // tokens per gate block
#define NGATE (N_TOK / TPB)   // 256 gate blocks

typedef __attribute__((ext_vector_type(8))) short short8;
typedef __attribute__((ext_vector_type(4))) short short4v;
typedef __attribute__((ext_vector_type(4))) float f32x4;

__device__ __forceinline__ short f2bf(float f) {
  __bf16 b = (__bf16)f;
  return *(short*)&b;
}
__device__ __forceinline__ float bf2f(short u) {
  union { unsigned int i; float f; } c;
  c.i = ((unsigned int)(unsigned short)u) << 16;
  return c.f;
}
__device__ __forceinline__ void gload(const void* g, void* l) {
  __builtin_amdgcn_global_load_lds(
      (const __attribute__((address_space(1))) uint32_t*)g,
      (__attribute__((address_space(3))) uint32_t*)l, 16, 0, 0);
}

// ---------------- prepass: batched gate (+X->bf16) AND W1 transpose ---------
// blocks 0..NGATE-1: gate for 32 tokens each, LDS-local expert lists, ONE
// global atomicAdd per expert per block (2048 total vs 16384 -- the R21
// prepass was serialized on 16K same-address L2 atomics, Guideline 12).
// blocks >= NGATE: one 64x64 W1 transpose tile.
__global__ __launch_bounds__(256) void prepass_kernel(
    const float* __restrict__ X, const float* __restrict__ Wg,
    const float* __restrict__ bg, int* __restrict__ cnt,
    int* __restrict__ bucket, float* __restrict__ pairw,
    unsigned short* __restrict__ Xb,
    const float* __restrict__ W1, unsigned short* __restrict__ W1t)
{
  const int tid = threadIdx.x;
  if (blockIdx.x < NGATE) {
    // ---- batched gate ----
    __shared__ float wsum[4][NE];
    __shared__ int lcnt[NE];
    __shared__ int gbase[NE];
    __shared__ int llist[NE][2 * TPB];
    if (tid < NE) lcnt[tid] = 0;
    __syncthreads();
    const float4* wg4 = (const float4*)Wg;
    float4 wv[NE];
#pragma unroll
    for (int e = 0; e < NE; ++e) wv[e] = wg4[e * (D_DIM / 4) + tid];
    const int wave = tid >> 6;

    for (int it = 0; it < TPB; ++it) {
      const int token = blockIdx.x * TPB + it;
      const float4 xv = ((const float4*)(X + (size_t)token * D_DIM))[tid];
      short4v o;
      o.x = f2bf(xv.x); o.y = f2bf(xv.y); o.z = f2bf(xv.z); o.w = f2bf(xv.w);
      ((short4v*)(Xb + (size_t)token * D_DIM))[tid] = o;

      float part[NE];
#pragma unroll
      for (int e = 0; e < NE; ++e)
        part[e] = fmaf(xv.x, wv[e].x, fmaf(xv.y, wv[e].y,
                  fmaf(xv.z, wv[e].z, xv.w * wv[e].w)));
#pragma unroll
      for (int e = 0; e < NE; ++e) {
#pragma unroll
        for (int off = 32; off > 0; off >>= 1) part[e] += __shfl_down(part[e], off);
      }
      if ((tid & 63) == 0) {
#pragma unroll
        for (int e = 0; e < NE; ++e) wsum[wave][e] = part[e];
      }
      __syncthreads();
      if (tid == 0) {
        float lg[NE];
#pragma unroll
        for (int e = 0; e < NE; ++e)
          lg[e] = wsum[0][e] + wsum[1][e] + wsum[2][e] + wsum[3][e] + bg[e];
        int e0 = 0;
#pragma unroll
        for (int e = 1; e < NE; ++e) if (lg[e] > lg[e0]) e0 = e;  // jax tie-break
        int e1 = (e0 == 0) ? 1 : 0;
#pragma unroll
        for (int e = 0; e < NE; ++e) if (e != e0 && lg[e] > lg[e1]) e1 = e;
        float p1 = expf(lg[e1] - lg[e0]);        // p0 = 1; softmax denom cancels
        float inv = 1.f / (1.f + p1);
        pairw[token * 2]     = inv;
        pairw[token * 2 + 1] = p1 * inv;
        llist[e0][lcnt[e0]++] = token * 2;       // single-lane LDS appends
        llist[e1][lcnt[e1]++] = token * 2 + 1;
      }
      __syncthreads();                           // wsum/lcnt stable for next it
    }
    if (tid < NE) gbase[tid] = atomicAdd(&cnt[tid], lcnt[tid]);
    __syncthreads();
#pragma unroll
    for (int e = 0; e < NE; ++e) {
      for (int i = tid; i < lcnt[e]; i += 256)
        bucket[e * CAP + gbase[e] + i] = llist[e][i];
    }
  } else {
    // ---- W1 transpose tile: src D x F (R=1024,C=4096) -> W1t [F][D] -------
    __shared__ float tileT[64][65];
    const int idx = blockIdx.x - NGATE;          // 0..8191
    const int bx = idx & 63;                     // c-tile (F)
    const int by = (idx >> 6) & 15;              // r-tile (D)
    const int ez = idx >> 10;
    const float* src = W1 + (size_t)ez * D_DIM * F_DIM;
    unsigned short* dst = W1t + (size_t)ez * D_DIM * F_DIM;
    const int c0 = bx * 64, r0 = by * 64;
    const int cx = tid & 15;
    const int ry = tid >> 4;
#pragma unroll
    for (int i = 0; i < 4; ++i) {
      const int row = ry + i * 16;
      const float4 v = *(const float4*)(src + (size_t)(r0 + row) * F_DIM + c0 + cx * 4);
      tileT[cx * 4 + 0][row] = v.x;
      tileT[cx * 4 + 1][row] = v.y;
      tileT[cx * 4 + 2][row] = v.z;
      tileT[cx * 4 + 3][row] = v.w;
    }
    __syncthreads();
#pragma unroll
    for (int i = 0; i < 4; ++i) {
      const int cc = ry + i * 16;
      short4v o;
      o.x = f2bf(tileT[cc][cx * 4 + 0]);
      o.y = f2bf(tileT[cc][cx * 4 + 1]);
      o.z = f2bf(tileT[cc][cx * 4 + 2]);
      o.w = f2bf(tileT[cc][cx * 4 + 3]);
      *(short4v*)(dst + (size_t)(c0 + cc) * D_DIM + r0 + cx * 4) = o;
    }
  }
}

// ---------------- prefix sums + pair->slot map (one launch) -----------------
__global__ __launch_bounds__(256) void prefix_fill_kernel(
    const int* __restrict__ cnt, int* __restrict__ expoff,
    int* __restrict__ toff, const int* __restrict__ bucket,
    int* __restrict__ pairslot)
{
  __shared__ int soff[NE];
  if (threadIdx.x == 0) {
    int s = 0, t = 0;
#pragma unroll
    for (int e = 0; e < NE; ++e) {
      expoff[e] = s; soff[e] = s;
      toff[e] = t;
      s += cnt[e];
      t += (cnt[e] + 255) >> 8;
    }
    toff[NE] = t;
  }
  __syncthreads();
  for (int e = 0; e < NE; ++e) {
    const int n = cnt[e], off = soff[e];
    for (int p = threadIdx.x; p < n; p += 256)
      pairslot[bucket[e * CAP + p]] = off + p;
  }
}

// ---------------- grouped expert GEMM: 256x256, 16 waves, ring-4 ------------
// R20/R21 core unchanged (ring-4 K=32 halves, vmcnt(4) flight, swizzle
// c^((r>>1)&3), 0 conflicts, VGPR 64, 1 block/CU).
// LAYER 1 ONLY: blocks bid >= NG are W2-TRANSPOSE workers riding the tail.
template<int LAYER>
__global__ __launch_bounds__(1024, 4) void moe_gemm(
    const unsigned short* __restrict__ Abase,
    const unsigned short* __restrict__ Bt,
    const float* __restrict__ bias,
    const int* __restrict__ cnt,
    const int* __restrict__ expoff,
    const int* __restrict__ toff,
    const int* __restrict__ bucket,
    unsigned short* __restrict__ OutA,
    unsigned short* __restrict__ OutB,
    const float* __restrict__ W2src,
    unsigned short* __restrict__ W2dst)
{
  constexpr int BM = 256, BN = 256;
  constexpr int KDIM = (LAYER == 1) ? D_DIM : F_DIM;
  constexpr int NDIM = (LAYER == 1) ? F_DIM : D_DIM;
  constexpr int KSPAN = (LAYER == 1) ? KDIM : (KDIM / 2);  // per-block K range
  constexpr int HALVES = KSPAN / 32;                       // 32 or 64
  constexpr int NG = (LAYER == 1) ? (MAXT * (F_DIM / 256))
                                  : (MAXT * (D_DIM / 256) * 2);  // GEMM blocks

  __shared__ __align__(16) char Alds[4 * 16384];   // 64 KiB ring-4
  __shared__ __align__(16) char Blds[4 * 16384];   // 64 KiB ring-4
  __shared__ int rowpair[BM];

  const int tid = threadIdx.x;

  if (LAYER == 1 && (int)blockIdx.x >= NG) {
    // ---- W2 transpose workers: src F x D (R=4096,C=1024) -> W2t [D][F] ----
    const int wblk = blockIdx.x - NG;
    const int grp = tid >> 8;
    const int gt = tid & 255;
    float* tileT = (float*)((grp < 2 ? Alds : Blds) + (grp & 1) * 20480);
    const int cx = gt & 15;
    const int ry = gt >> 4;
    for (int it = 0; it < 8; ++it) {
      const int t = wblk * 32 + grp * 8 + it;
      const int ct = t & 15;                 // c-tile (D)
      const int rt = (t >> 4) & 63;          // r-tile (F)
      const int ez = t >> 10;
      const float* src = W2src + (size_t)ez * D_DIM * F_DIM;
      unsigned short* dst = W2dst + (size_t)ez * D_DIM * F_DIM;
      const int c0 = ct * 64, r0 = rt * 64;
#pragma unroll
      for (int i = 0; i < 4; ++i) {
        const int row = ry + i * 16;
        const float4 v = *(const float4*)(src + (size_t)(r0 + row) * D_DIM + c0 + cx * 4);
        tileT[(cx * 4 + 0) * 65 + row] = v.x;
        tileT[(cx * 4 + 1) * 65 + row] = v.y;
        tileT[(cx * 4 + 2) * 65 + row] = v.z;
        tileT[(cx * 4 + 3) * 65 + row] = v.w;
      }
      __syncthreads();
#pragma unroll
      for (int i = 0; i < 4; ++i) {
        const int cc = ry + i * 16;
        short4v o;
        o.x = f2bf(tileT[cc * 65 + cx * 4 + 0]);
        o.y = f2bf(tileT[cc * 65 + cx * 4 + 1]);
        o.z = f2bf(tileT[cc * 65 + cx * 4 + 2]);
        o.w = f2bf(tileT[cc * 65 + cx * 4 + 3]);
        *(short4v*)(dst + (size_t)(c0 + cc) * F_DIM + r0 + cx * 4) = o;
      }
      __syncthreads();
    }
    return;
  }

  // ---- GEMM path ----
  const int q = NG >> 3;
  const int g = ((int)blockIdx.x & 7) * q + ((int)blockIdx.x >> 3);
  const int cc = g / MAXT;                 // L1: ntile; L2: (ntile<<1)|split
  const int mt = g % MAXT;
  if (mt >= toff[NE]) return;
  int e = 0;
  while (mt >= toff[e + 1]) ++e;
  const int mtile = mt - toff[e];
  const int cnt_e = cnt[e];
  const int eoff = expoff[e];
  const int ntile = (LAYER == 1) ? cc : (cc >> 1);
  const int split = (LAYER == 1) ? 0 : (cc & 1);
  const int kbase = split * KSPAN;

  const int lane = tid & 63;
  const int l15 = lane & 15, lhi = lane >> 4;
  const int wid = tid >> 6;
  const int uw = __builtin_amdgcn_readfirstlane(wid);
  const int wm = wid >> 2, wn = wid & 3;           // 4M x 4N waves

  if (LAYER == 1) {
    if (tid < BM) {
      int pos = mtile * BM + tid;
      rowpair[tid] = (pos < cnt_e) ? bucket[e * CAP + pos] : -1;
    }
    __syncthreads();
  }

  const unsigned short* a_src;
  const unsigned short* b_src;
  {
    int ci = tid;
    int r = ci >> 2, c = ci & 3;
    int sc = c ^ ((r >> 1) & 3);
    size_t arow;
    if (LAYER == 1) {
      int pair = rowpair[r];
      arow = (pair < 0) ? 0 : (size_t)(pair >> 1);
    } else {
      arow = (size_t)(eoff + mtile * BM + r);      // contiguous slot rows
    }
    a_src = Abase + arow * KDIM + kbase + sc * 8;
    b_src = Bt + (size_t)e * NDIM * KDIM +
            (size_t)(ntile * BN + r) * KDIM + kbase + sc * 8;
  }

  auto stage = [&](int h) {
    const int s = h & 3;
    gload(a_src + h * 32, &Alds[0] + s * 16384 + uw * 1024);
    gload(b_src + h * 32, &Blds[0] + s * 16384 + uw * 1024);
  };

  f32x4 acc[4][4];
#pragma unroll
  for (int m = 0; m < 4; ++m)
#pragma unroll
    for (int n = 0; n < 4; ++n) acc[m][n] = (f32x4){0.f, 0.f, 0.f, 0.f};

  stage(0); stage(1); stage(2);            // 6 insts/thread outstanding

  for (int H = 0; H < HALVES; ++H) {
    if (H + 2 < HALVES)      asm volatile("s_waitcnt vmcnt(4)" ::: "memory");
    else if (H + 1 < HALVES) asm volatile("s_waitcnt vmcnt(2)" ::: "memory");
    else                     asm volatile("s_waitcnt vmcnt(0)" ::: "memory");
    __builtin_amdgcn_sched_barrier(0);
    __builtin_amdgcn_s_barrier();

    const char* aSlot = &Alds[0] + (H & 3) * 16384;
    const char* bSlot = &Blds[0] + (H & 3) * 16384;
    short8 bfr[4], af[4];
#pragma unroll
    for (int n = 0; n < 4; ++n) {
      const int row = wn * 64 + n * 16 + l15;
      bfr[n] = *(const short8*)(bSlot + row * 64 + ((lhi ^ ((row >> 1) & 3)) << 4));
    }
#pragma unroll
    for (int m = 0; m < 4; ++m) {
      const int row = wm * 64 + m * 16 + l15;
      af[m] = *(const short8*)(aSlot + row * 64 + ((lhi ^ ((row >> 1) & 3)) << 4));
    }
    if (H + 3 < HALVES) stage(H + 3);      // refills slot (H-1)&3
    asm volatile("s_waitcnt lgkmcnt(0)" ::: "memory");
    __builtin_amdgcn_sched_barrier(0);
    __builtin_amdgcn_s_setprio(1);
#pragma unroll
    for (int m = 0; m < 4; ++m)
#pragma unroll
      for (int n = 0; n < 4; ++n)
        acc[m][n] = __builtin_amdgcn_mfma_f32_16x16x32_bf16(af[m], bfr[n], acc[m][n], 0, 0, 0);
    __builtin_amdgcn_s_setprio(0);
  }

  // epilogue: C/D layout col = lane&15, row = (lane>>4)*4 + j
#pragma unroll
  for (int m = 0; m < 4; ++m) {
#pragma unroll
    for (int j = 0; j < 4; ++j) {
      const int row = wm * 64 + m * 16 + lhi * 4 + j;
      if (mtile * BM + row >= cnt_e) continue;
      const size_t slot = (size_t)(eoff + mtile * BM + row);
#pragma unroll
      for (int n = 0; n < 4; ++n) {
        const int col = ntile * BN + wn * 64 + n * 16 + l15;
        if (LAYER == 1) {
          float val = acc[m][n][j] + bias[e * NDIM + col];
          float gl = 0.5f * val * (1.f + erff(val * 0.70710678118654752f));
          OutA[slot * F_DIM + col] = (unsigned short)f2bf(gl);
        } else {
          float val = acc[m][n][j] + (split == 0 ? bias[e * NDIM + col] : 0.f);
          unsigned short* dst = (split == 0) ? OutA : OutB;
          dst[slot * D_DIM + col] = (unsigned short)f2bf(val);
        }
      }
    }
  }
}

// ---------------- combine: out[t] = w0*(yA+yB)[s0] + w1*(yA+yB)[s1] ---------
__global__ __launch_bounds__(256) void combine_kernel(
    const unsigned short* __restrict__ ybufA, const unsigned short* __restrict__ ybufB,
    const float* __restrict__ pairw, const int* __restrict__ pairslot,
    float* __restrict__ out)
{
  const int t = blockIdx.x;
  const int tid = threadIdx.x;
  const float w0 = pairw[t * 2], w1 = pairw[t * 2 + 1];
  const int s0 = pairslot[t * 2], s1 = pairslot[t * 2 + 1];
  const short4v a0 = ((const short4v*)(ybufA + (size_t)s0 * D_DIM))[tid];
  const short4v b0 = ((const short4v*)(ybufB + (size_t)s0 * D_DIM))[tid];
  const short4v a1 = ((const short4v*)(ybufA + (size_t)s1 * D_DIM))[tid];
  const short4v b1 = ((const short4v*)(ybufB + (size_t)s1 * D_DIM))[tid];
  float4 o;
  o.x = w0 * (bf2f(a0.x) + bf2f(b0.x)) + w1 * (bf2f(a1.x) + bf2f(b1.x));
  o.y = w0 * (bf2f(a0.y) + bf2f(b0.y)) + w1 * (bf2f(a1.y) + bf2f(b1.y));
  o.z = w0 * (bf2f(a0.z) + bf2f(b0.z)) + w1 * (bf2f(a1.z) + bf2f(b1.z));
  o.w = w0 * (bf2f(a0.w) + bf2f(b0.w)) + w1 * (bf2f(a1.w) + bf2f(b1.w));
  ((float4*)(out + (size_t)t * D_DIM))[tid] = o;
}

// ---------------- launch ----------------------------------------------------
extern "C" void kernel_launch(void* const* d_in, const int* in_sizes, int n_in,
                              void* d_out, int out_size, void* d_ws, size_t ws_size,
                              hipStream_t stream)
{
  const float* X  = (const float*)d_in[0];
  const float* Wg = (const float*)d_in[1];
  const float* bg = (const float*)d_in[2];
  const float* W1 = (const float*)d_in[3];
  const float* b1 = (const float*)d_in[4];
  const float* W2 = (const float*)d_in[5];
  const float* b2 = (const float*)d_in[6];
  float* out = (float*)d_out;

  char* ws = (char*)d_ws;
  size_t off = 0;
  auto alloc = [&](size_t sz) {
    size_t o = off;
    off = (off + sz + 255) & ~(size_t)255;
    return o;
  };
  int*            cnt      = (int*)(ws + alloc(NE * sizeof(int)));
  int*            expoff   = (int*)(ws + alloc(NE * sizeof(int)));
  int*            toff     = (int*)(ws + alloc((NE + 1) * sizeof(int)));
  int*            bucket   = (int*)(ws + alloc((size_t)NE * CAP * sizeof(int)));
  float*          pairw    = (float*)(ws + alloc((size_t)N_TOK * 2 * sizeof(float)));
  int*            pairslot = (int*)(ws + alloc((size_t)N_TOK * 2 * sizeof(int)));
  unsigned short* Xb       = (unsigned short*)(ws + alloc((size_t)N_TOK * D_DIM * 2));
  unsigned short* W1t      = (unsigned short*)(ws + alloc((size_t)NE * D_DIM * F_DIM * 2));
  unsigned short* W2t      = (unsigned short*)(ws + alloc((size_t)NE * D_DIM * F_DIM * 2));
  unsigned short* hmid     = (unsigned short*)(ws + alloc((size_t)(N_TOK * 2 + 256) * F_DIM * 2));
  unsigned short* ybufB    = (unsigned short*)(ws + alloc((size_t)(N_TOK * 2 + 256) * D_DIM * 2));
  unsigned short* ybufA    = W1t;   // W1t dead after GEMM1

  hipMemsetAsync(cnt, 0, NE * sizeof(int), stream);

  prepass_kernel<<<NGATE + NE * 1024, 256, 0, stream>>>(
      X, Wg, bg, cnt, bucket, pairw, Xb, W1, W1t);
  prefix_fill_kernel<<<1, 256, 0, stream>>>(cnt, expoff, toff, bucket, pairslot);

  moe_gemm<1><<<MAXT * (F_DIM / 256) + 256, 1024, 0, stream>>>(  // 1152 GEMM + 256 W2T
      Xb, W1t, b1, cnt, expoff, toff, bucket, hmid, nullptr, W2, W2t);
  moe_gemm<2><<<MAXT * (D_DIM / 256) * 2, 1024, 0, stream>>>(    // 576 blocks
      hmid, W2t, b2, cnt, expoff, toff, bucket, ybufA, ybufB, nullptr, nullptr);
  combine_kernel<<<N_TOK, 256, 0, stream>>>(ybufA, ybufB, pairw, pairslot, out);
}

// Round 23
// 533.606 us; speedup vs baseline: 9.9742x; 1.0411x over previous
//
#include <hip/hip_runtime.h>
#include <hip/hip_bf16.h>
#include <cstdint>
#include <math.h>

#define N_TOK 8192
#define D_DIM 1024
#define F_DIM 4096
#define NE 8
#define CAP 8192
#define MAXT 72    // max sum_e ceil(cnt_e/256) = 71, padded
#define TPB 16     // tokens per gate block
#define NGATE (N_TOK / TPB)   // 512 gate blocks

typedef __attribute__((ext_vector_type(8))) short short8;
typedef __attribute__((ext_vector_type(4))) short short4v;
typedef __attribute__((ext_vector_type(4))) float f32x4;

__device__ __forceinline__ short f2bf(float f) {
  __bf16 b = (__bf16)f;
  return *(short*)&b;
}
__device__ __forceinline__ float bf2f(short u) {
  union { unsigned int i; float f; } c;
  c.i = ((unsigned int)(unsigned short)u) << 16;
  return c.f;
}
__device__ __forceinline__ void gload(const void* g, void* l) {
  __builtin_amdgcn_global_load_lds(
      (const __attribute__((address_space(1))) uint32_t*)g,
      (__attribute__((address_space(3))) uint32_t*)l, 16, 0, 0);
}

// ---------------- prepass: batched gate (+X->bf16) AND W1 transpose ---------
// blocks 0..NGATE-1: gate for 16 tokens each (2 blocks/CU, halved serial
// chain), LDS-local expert lists, ONE atomicAdd per expert per block.
// blocks >= NGATE: one 128x64 W1 transpose tile -- BOTH read and write
// granules are 256 B contiguous (the old 64x64 tile wrote 128 B granules at
// 2 KB stride -> strided-write collapse). LDS row pad 129 -> <=2 lanes/bank.
__global__ __launch_bounds__(256) void prepass_kernel(
    const float* __restrict__ X, const float* __restrict__ Wg,
    const float* __restrict__ bg, int* __restrict__ cnt,
    int* __restrict__ bucket, float* __restrict__ pairw,
    unsigned short* __restrict__ Xb,
    const float* __restrict__ W1, unsigned short* __restrict__ W1t)
{
  const int tid = threadIdx.x;
  if (blockIdx.x < NGATE) {
    // ---- batched gate ----
    __shared__ float wsum[4][NE];
    __shared__ int lcnt[NE];
    __shared__ int gbase[NE];
    __shared__ int llist[NE][2 * TPB];
    if (tid < NE) lcnt[tid] = 0;
    __syncthreads();
    const float4* wg4 = (const float4*)Wg;
    float4 wv[NE];
#pragma unroll
    for (int e = 0; e < NE; ++e) wv[e] = wg4[e * (D_DIM / 4) + tid];
    const int wave = tid >> 6;

    for (int it = 0; it < TPB; ++it) {
      const int token = blockIdx.x * TPB + it;
      const float4 xv = ((const float4*)(X + (size_t)token * D_DIM))[tid];
      short4v o;
      o.x = f2bf(xv.x); o.y = f2bf(xv.y); o.z = f2bf(xv.z); o.w = f2bf(xv.w);
      ((short4v*)(Xb + (size_t)token * D_DIM))[tid] = o;

      float part[NE];
#pragma unroll
      for (int e = 0; e < NE; ++e)
        part[e] = fmaf(xv.x, wv[e].x, fmaf(xv.y, wv[e].y,
                  fmaf(xv.z, wv[e].z, xv.w * wv[e].w)));
#pragma unroll
      for (int e = 0; e < NE; ++e) {
#pragma unroll
        for (int off = 32; off > 0; off >>= 1) part[e] += __shfl_down(part[e], off);
      }
      if ((tid & 63) == 0) {
#pragma unroll
        for (int e = 0; e < NE; ++e) wsum[wave][e] = part[e];
      }
      __syncthreads();
      if (tid == 0) {
        float lg[NE];
#pragma unroll
        for (int e = 0; e < NE; ++e)
          lg[e] = wsum[0][e] + wsum[1][e] + wsum[2][e] + wsum[3][e] + bg[e];
        int e0 = 0;
#pragma unroll
        for (int e = 1; e < NE; ++e) if (lg[e] > lg[e0]) e0 = e;  // jax tie-break
        int e1 = (e0 == 0) ? 1 : 0;
#pragma unroll
        for (int e = 0; e < NE; ++e) if (e != e0 && lg[e] > lg[e1]) e1 = e;
        float p1 = expf(lg[e1] - lg[e0]);        // p0 = 1; softmax denom cancels
        float inv = 1.f / (1.f + p1);
        pairw[token * 2]     = inv;
        pairw[token * 2 + 1] = p1 * inv;
        llist[e0][lcnt[e0]++] = token * 2;       // single-lane LDS appends
        llist[e1][lcnt[e1]++] = token * 2 + 1;
      }
      __syncthreads();                           // wsum/lcnt stable for next it
    }
    if (tid < NE) gbase[tid] = atomicAdd(&cnt[tid], lcnt[tid]);
    __syncthreads();
#pragma unroll
    for (int e = 0; e < NE; ++e) {
      for (int i = tid; i < lcnt[e]; i += 256)
        bucket[e * CAP + gbase[e] + i] = llist[e][i];
    }
  } else {
    // ---- W1 transpose tile 128(D) x 64(F): src [D][F] -> W1t [F][D] -------
    __shared__ float tileT[64 * 129];            // [Flocal][Dlocal(pad 129)]
    const int idx = blockIdx.x - NGATE;          // 0..4095
    const int ez = idx >> 9;
    const int rem = idx & 511;
    const int d0 = (rem >> 6) * 128;             // 8 D-tiles
    const int f0 = (rem & 63) * 64;              // 64 F-tiles
    const float* src = W1 + (size_t)ez * D_DIM * F_DIM;
    unsigned short* dst = W1t + (size_t)ez * D_DIM * F_DIM;
    const int cx = tid & 15;                     // F float4 group
    const int ry = tid >> 4;                     // 16 D rows / pass
#pragma unroll
    for (int i = 0; i < 8; ++i) {
      const int row = ry + i * 16;               // Dlocal 0..127
      const float4 v = *(const float4*)(src + (size_t)(d0 + row) * F_DIM + f0 + cx * 4);
      tileT[(cx * 4 + 0) * 129 + row] = v.x;
      tileT[(cx * 4 + 1) * 129 + row] = v.y;
      tileT[(cx * 4 + 2) * 129 + row] = v.z;
      tileT[(cx * 4 + 3) * 129 + row] = v.w;
    }
    __syncthreads();
    const int dx = tid & 31;                     // D short4 group (128 elems)
    const int fy = tid >> 5;                     // 8 F rows / pass
#pragma unroll
    for (int i = 0; i < 8; ++i) {
      const int fl = fy + i * 8;                 // Flocal 0..63
      short4v o;
      o.x = f2bf(tileT[fl * 129 + dx * 4 + 0]);
      o.y = f2bf(tileT[fl * 129 + dx * 4 + 1]);
      o.z = f2bf(tileT[fl * 129 + dx * 4 + 2]);
      o.w = f2bf(tileT[fl * 129 + dx * 4 + 3]);
      *(short4v*)(dst + (size_t)(f0 + fl) * D_DIM + d0 + dx * 4) = o;  // 256B/row
    }
  }
}

// ---------------- prefix sums + pair->slot map (one launch) -----------------
__global__ __launch_bounds__(256) void prefix_fill_kernel(
    const int* __restrict__ cnt, int* __restrict__ expoff,
    int* __restrict__ toff, const int* __restrict__ bucket,
    int* __restrict__ pairslot)
{
  __shared__ int soff[NE];
  if (threadIdx.x == 0) {
    int s = 0, t = 0;
#pragma unroll
    for (int e = 0; e < NE; ++e) {
      expoff[e] = s; soff[e] = s;
      toff[e] = t;
      s += cnt[e];
      t += (cnt[e] + 255) >> 8;
    }
    toff[NE] = t;
  }
  __syncthreads();
  for (int e = 0; e < NE; ++e) {
    const int n = cnt[e], off = soff[e];
    for (int p = threadIdx.x; p < n; p += 256)
      pairslot[bucket[e * CAP + p]] = off + p;
  }
}

// ---------------- grouped expert GEMM: 256x256, 16 waves, ring-4 ------------
// R20-R22 core unchanged (ring-4 K=32 halves, vmcnt(4) flight, swizzle
// c^((r>>1)&3), 0 conflicts, VGPR 64, 1 block/CU).
// LAYER 1 ONLY: blocks bid >= NG are W2-TRANSPOSE workers (256 blocks x
// 2 groups(512thr) x 8 tiles of 128(F)x64(D); 256B read AND write granules).
template<int LAYER>
__global__ __launch_bounds__(1024, 4) void moe_gemm(
    const unsigned short* __restrict__ Abase,
    const unsigned short* __restrict__ Bt,
    const float* __restrict__ bias,
    const int* __restrict__ cnt,
    const int* __restrict__ expoff,
    const int* __restrict__ toff,
    const int* __restrict__ bucket,
    unsigned short* __restrict__ OutA,
    unsigned short* __restrict__ OutB,
    const float* __restrict__ W2src,
    unsigned short* __restrict__ W2dst)
{
  constexpr int BM = 256, BN = 256;
  constexpr int KDIM = (LAYER == 1) ? D_DIM : F_DIM;
  constexpr int NDIM = (LAYER == 1) ? F_DIM : D_DIM;
  constexpr int KSPAN = (LAYER == 1) ? KDIM : (KDIM / 2);  // per-block K range
  constexpr int HALVES = KSPAN / 32;                       // 32 or 64
  constexpr int NG = (LAYER == 1) ? (MAXT * (F_DIM / 256))
                                  : (MAXT * (D_DIM / 256) * 2);  // GEMM blocks

  __shared__ __align__(16) char Alds[4 * 16384];   // 64 KiB ring-4
  __shared__ __align__(16) char Blds[4 * 16384];   // 64 KiB ring-4
  __shared__ int rowpair[BM];

  const int tid = threadIdx.x;

  if (LAYER == 1 && (int)blockIdx.x >= NG) {
    // ---- W2 transpose workers: tile 128(F) x 64(D); src [F][D] -> [D][F] --
    const int wblk = blockIdx.x - NG;
    const int grp = tid >> 9;                    // 2 groups of 512
    const int gt = tid & 511;
    float* tileT = (float*)(grp == 0 ? Alds : Blds);   // 33 KB each
    const int cx = gt & 15;                      // D float4 group (64 floats)
    const int ry = gt >> 4;                      // 32 F rows / pass
    const int dx = gt & 31;                      // F short4 group (128 elems)
    const int fy = gt >> 5;                      // 16 D rows / pass
    for (int it = 0; it < 8; ++it) {
      const int t = wblk * 16 + grp * 8 + it;    // 0..4095
      const int ez = t >> 9;
      const int rem = t & 511;
      const int f0 = (rem >> 4) * 128;           // 32 F-tiles
      const int d0 = (rem & 15) * 64;            // 16 D-tiles
      const float* src = W2src + (size_t)ez * D_DIM * F_DIM;
      unsigned short* dst = W2dst + (size_t)ez * D_DIM * F_DIM;
#pragma unroll
      for (int i = 0; i < 4; ++i) {
        const int row = ry + i * 32;             // Flocal 0..127
        const float4 v = *(const float4*)(src + (size_t)(f0 + row) * D_DIM + d0 + cx * 4);
        tileT[(cx * 4 + 0) * 129 + row] = v.x;
        tileT[(cx * 4 + 1) * 129 + row] = v.y;
        tileT[(cx * 4 + 2) * 129 + row] = v.z;
        tileT[(cx * 4 + 3) * 129 + row] = v.w;
      }
      __syncthreads();
#pragma unroll
      for (int i = 0; i < 4; ++i) {
        const int dl = fy + i * 16;              // Dlocal 0..63
        short4v o;
        o.x = f2bf(tileT[dl * 129 + dx * 4 + 0]);
        o.y = f2bf(tileT[dl * 129 + dx * 4 + 1]);
        o.z = f2bf(tileT[dl * 129 + dx * 4 + 2]);
        o.w = f2bf(tileT[dl * 129 + dx * 4 + 3]);
        *(short4v*)(dst + (size_t)(d0 + dl) * F_DIM + f0 + dx * 4) = o;  // 256B
      }
      __syncthreads();
    }
    return;
  }

  // ---- GEMM path ----
  const int q = NG >> 3;
  const int g = ((int)blockIdx.x & 7) * q + ((int)blockIdx.x >> 3);
  const int cc = g / MAXT;                 // L1: ntile; L2: (ntile<<1)|split
  const int mt = g % MAXT;
  if (mt >= toff[NE]) return;
  int e = 0;
  while (mt >= toff[e + 1]) ++e;
  const int mtile = mt - toff[e];
  const int cnt_e = cnt[e];
  const int eoff = expoff[e];
  const int ntile = (LAYER == 1) ? cc : (cc >> 1);
  const int split = (LAYER == 1) ? 0 : (cc & 1);
  const int kbase = split * KSPAN;

  const int lane = tid & 63;
  const int l15 = lane & 15, lhi = lane >> 4;
  const int wid = tid >> 6;
  const int uw = __builtin_amdgcn_readfirstlane(wid);
  const int wm = wid >> 2, wn = wid & 3;           // 4M x 4N waves

  if (LAYER == 1) {
    if (tid < BM) {
      int pos = mtile * BM + tid;
      rowpair[tid] = (pos < cnt_e) ? bucket[e * CAP + pos] : -1;
    }
    __syncthreads();
  }

  const unsigned short* a_src;
  const unsigned short* b_src;
  {
    int ci = tid;
    int r = ci >> 2, c = ci & 3;
    int sc = c ^ ((r >> 1) & 3);
    size_t arow;
    if (LAYER == 1) {
      int pair = rowpair[r];
      arow = (pair < 0) ? 0 : (size_t)(pair >> 1);
    } else {
      arow = (size_t)(eoff + mtile * BM + r);      // contiguous slot rows
    }
    a_src = Abase + arow * KDIM + kbase + sc * 8;
    b_src = Bt + (size_t)e * NDIM * KDIM +
            (size_t)(ntile * BN + r) * KDIM + kbase + sc * 8;
  }

  auto stage = [&](int h) {
    const int s = h & 3;
    gload(a_src + h * 32, &Alds[0] + s * 16384 + uw * 1024);
    gload(b_src + h * 32, &Blds[0] + s * 16384 + uw * 1024);
  };

  f32x4 acc[4][4];
#pragma unroll
  for (int m = 0; m < 4; ++m)
#pragma unroll
    for (int n = 0; n < 4; ++n) acc[m][n] = (f32x4){0.f, 0.f, 0.f, 0.f};

  stage(0); stage(1); stage(2);            // 6 insts/thread outstanding

  for (int H = 0; H < HALVES; ++H) {
    if (H + 2 < HALVES)      asm volatile("s_waitcnt vmcnt(4)" ::: "memory");
    else if (H + 1 < HALVES) asm volatile("s_waitcnt vmcnt(2)" ::: "memory");
    else                     asm volatile("s_waitcnt vmcnt(0)" ::: "memory");
    __builtin_amdgcn_sched_barrier(0);
    __builtin_amdgcn_s_barrier();

    const char* aSlot = &Alds[0] + (H & 3) * 16384;
    const char* bSlot = &Blds[0] + (H & 3) * 16384;
    short8 bfr[4], af[4];
#pragma unroll
    for (int n = 0; n < 4; ++n) {
      const int row = wn * 64 + n * 16 + l15;
      bfr[n] = *(const short8*)(bSlot + row * 64 + ((lhi ^ ((row >> 1) & 3)) << 4));
    }
#pragma unroll
    for (int m = 0; m < 4; ++m) {
      const int row = wm * 64 + m * 16 + l15;
      af[m] = *(const short8*)(aSlot + row * 64 + ((lhi ^ ((row >> 1) & 3)) << 4));
    }
    if (H + 3 < HALVES) stage(H + 3);      // refills slot (H-1)&3
    asm volatile("s_waitcnt lgkmcnt(0)" ::: "memory");
    __builtin_amdgcn_sched_barrier(0);
    __builtin_amdgcn_s_setprio(1);
#pragma unroll
    for (int m = 0; m < 4; ++m)
#pragma unroll
      for (int n = 0; n < 4; ++n)
        acc[m][n] = __builtin_amdgcn_mfma_f32_16x16x32_bf16(af[m], bfr[n], acc[m][n], 0, 0, 0);
    __builtin_amdgcn_s_setprio(0);
  }

  // epilogue: C/D layout col = lane&15, row = (lane>>4)*4 + j
#pragma unroll
  for (int m = 0; m < 4; ++m) {
#pragma unroll
    for (int j = 0; j < 4; ++j) {
      const int row = wm * 64 + m * 16 + lhi * 4 + j;
      if (mtile * BM + row >= cnt_e) continue;
      const size_t slot = (size_t)(eoff + mtile * BM + row);
#pragma unroll
      for (int n = 0; n < 4; ++n) {
        const int col = ntile * BN + wn * 64 + n * 16 + l15;
        if (LAYER == 1) {
          float val = acc[m][n][j] + bias[e * NDIM + col];
          float gl = 0.5f * val * (1.f + erff(val * 0.70710678118654752f));
          OutA[slot * F_DIM + col] = (unsigned short)f2bf(gl);
        } else {
          float val = acc[m][n][j] + (split == 0 ? bias[e * NDIM + col] : 0.f);
          unsigned short* dst = (split == 0) ? OutA : OutB;
          dst[slot * D_DIM + col] = (unsigned short)f2bf(val);
        }
      }
    }
  }
}

// ---------------- combine: out[t] = w0*(yA+yB)[s0] + w1*(yA+yB)[s1] ---------
__global__ __launch_bounds__(256) void combine_kernel(
    const unsigned short* __restrict__ ybufA, const unsigned short* __restrict__ ybufB,
    const float* __restrict__ pairw, const int* __restrict__ pairslot,
    float* __restrict__ out)
{
  const int t = blockIdx.x;
  const int tid = threadIdx.x;
  const float w0 = pairw[t * 2], w1 = pairw[t * 2 + 1];
  const int s0 = pairslot[t * 2], s1 = pairslot[t * 2 + 1];
  const short4v a0 = ((const short4v*)(ybufA + (size_t)s0 * D_DIM))[tid];
  const short4v b0 = ((const short4v*)(ybufB + (size_t)s0 * D_DIM))[tid];
  const short4v a1 = ((const short4v*)(ybufA + (size_t)s1 * D_DIM))[tid];
  const short4v b1 = ((const short4v*)(ybufB + (size_t)s1 * D_DIM))[tid];
  float4 o;
  o.x = w0 * (bf2f(a0.x) + bf2f(b0.x)) + w1 * (bf2f(a1.x) + bf2f(b1.x));
  o.y = w0 * (bf2f(a0.y) + bf2f(b0.y)) + w1 * (bf2f(a1.y) + bf2f(b1.y));
  o.z = w0 * (bf2f(a0.z) + bf2f(b0.z)) + w1 * (bf2f(a1.z) + bf2f(b1.z));
  o.w = w0 * (bf2f(a0.w) + bf2f(b0.w)) + w1 * (bf2f(a1.w) + bf2f(b1.w));
  ((float4*)(out + (size_t)t * D_DIM))[tid] = o;
}

// ---------------- launch ----------------------------------------------------
extern "C" void kernel_launch(void* const* d_in, const int* in_sizes, int n_in,
                              void* d_out, int out_size, void* d_ws, size_t ws_size,
                              hipStream_t stream)
{
  const float* X  = (const float*)d_in[0];
  const float* Wg = (const float*)d_in[1];
  const float* bg = (const float*)d_in[2];
  const float* W1 = (const float*)d_in[3];
  const float* b1 = (const float*)d_in[4];
  const float* W2 = (const float*)d_in[5];
  const float* b2 = (const float*)d_in[6];
  float* out = (float*)d_out;

  char* ws = (char*)d_ws;
  size_t off = 0;
  auto alloc = [&](size_t sz) {
    size_t o = off;
    off = (off + sz + 255) & ~(size_t)255;
    return o;
  };
  int*            cnt      = (int*)(ws + alloc(NE * sizeof(int)));
  int*            expoff   = (int*)(ws + alloc(NE * sizeof(int)));
  int*            toff     = (int*)(ws + alloc((NE + 1) * sizeof(int)));
  int*            bucket   = (int*)(ws + alloc((size_t)NE * CAP * sizeof(int)));
  float*          pairw    = (float*)(ws + alloc((size_t)N_TOK * 2 * sizeof(float)));
  int*            pairslot = (int*)(ws + alloc((size_t)N_TOK * 2 * sizeof(int)));
  unsigned short* Xb       = (unsigned short*)(ws + alloc((size_t)N_TOK * D_DIM * 2));
  unsigned short* W1t      = (unsigned short*)(ws + alloc((size_t)NE * D_DIM * F_DIM * 2));
  unsigned short* W2t      = (unsigned short*)(ws + alloc((size_t)NE * D_DIM * F_DIM * 2));
  unsigned short* hmid     = (unsigned short*)(ws + alloc((size_t)(N_TOK * 2 + 256) * F_DIM * 2));
  unsigned short* ybufB    = (unsigned short*)(ws + alloc((size_t)(N_TOK * 2 + 256) * D_DIM * 2));
  unsigned short* ybufA    = W1t;   // W1t dead after GEMM1

  hipMemsetAsync(cnt, 0, NE * sizeof(int), stream);

  prepass_kernel<<<NGATE + NE * 512, 256, 0, stream>>>(
      X, Wg, bg, cnt, bucket, pairw, Xb, W1, W1t);
  prefix_fill_kernel<<<1, 256, 0, stream>>>(cnt, expoff, toff, bucket, pairslot);

  moe_gemm<1><<<MAXT * (F_DIM / 256) + 256, 1024, 0, stream>>>(  // 1152 GEMM + 256 W2T
      Xb, W1t, b1, cnt, expoff, toff, bucket, hmid, nullptr, W2, W2t);
  moe_gemm<2><<<MAXT * (D_DIM / 256) * 2, 1024, 0, stream>>>(    // 576 blocks
      hmid, W2t, b2, cnt, expoff, toff, bucket, ybufA, ybufB, nullptr, nullptr);
  combine_kernel<<<N_TOK, 256, 0, stream>>>(ybufA, ybufB, pairw, pairslot, out);
}